// Round 1
// 654.385 us; speedup vs baseline: 1.1069x; 1.1069x over previous
//
#include <hip/hip_runtime.h>
#include <math.h>

// MultiScaleTransformerGSM on MI355X (gfx950).
// LN+ReLU(+bf16 x copy) -> per branch: dwconv -> gate GEMM (double-buffered
// global_load_lds staging, pure-write bf16 epilogue w/ folded softmax weight)
// -> standalone fusion materialization -> proj1 GEMM -> proj2 GEMM + residual.
// R1: (a) fused tensor materialized once (kills 18x gather re-read in proj1),
//     (b) 2-phase LDS double-buffer prefetch in all GEMMs (one barrier/K-step,
//         next-tile loads overlap current-tile ds_read+MFMA).

#define MROWS 25216   // B*T*N = 8*16*197
#define CD    768
#define NTOK  197
#define TFR   16

typedef __attribute__((ext_vector_type(8))) short short8;
typedef __attribute__((ext_vector_type(4))) float floatx4;
typedef unsigned int u32;

__device__ __forceinline__ unsigned short f2bf(float f) {
    union { float f; unsigned u; } v; v.f = f;
    unsigned r = v.u + 0x7FFFu + ((v.u >> 16) & 1u);
    return (unsigned short)(r >> 16);
}
__device__ __forceinline__ float bf2f(unsigned short h) {
    union { unsigned u; float f; } v; v.u = ((unsigned)h) << 16;
    return v.f;
}

// async global->LDS, 16B per lane; LDS dest = wave-uniform base + lane*16
__device__ __forceinline__ void gl2lds16(const void* g, void* l) {
    __builtin_amdgcn_global_load_lds(
        (__attribute__((address_space(1))) void*)(unsigned long long)g,
        (__attribute__((address_space(3))) void*)(u32)(unsigned long long)l,
        16, 0, 0);
}

// ---------------- LayerNorm + ReLU -> bf16 (also emits bf16 copy of x) ----------------
__global__ __launch_bounds__(256)
void ln_relu_kernel(const float* __restrict__ x, const float* __restrict__ g,
                    const float* __restrict__ b, unsigned short* __restrict__ xn,
                    unsigned short* __restrict__ xb) {
    int row = blockIdx.x;
    int tid = threadIdx.x;
    const float* xr = x + (size_t)row * CD;
    float v0 = xr[tid], v1 = xr[tid + 256], v2 = xr[tid + 512];
    float s = v0 + v1 + v2;
    __shared__ float red[8];
#pragma unroll
    for (int off = 32; off; off >>= 1) s += __shfl_down(s, off, 64);
    int lane = tid & 63, w = tid >> 6;
    if (lane == 0) red[w] = s;
    __syncthreads();
    float mean = (red[0] + red[1] + red[2] + red[3]) * (1.0f / CD);
    float d0 = v0 - mean, d1 = v1 - mean, d2 = v2 - mean;
    float s2 = d0 * d0 + d1 * d1 + d2 * d2;
#pragma unroll
    for (int off = 32; off; off >>= 1) s2 += __shfl_down(s2, off, 64);
    if (lane == 0) red[4 + w] = s2;
    __syncthreads();
    float var = (red[4] + red[5] + red[6] + red[7]) * (1.0f / CD);
    float inv = rsqrtf(var + 1e-5f);
    unsigned short* xo = xn + (size_t)row * CD;
    unsigned short* xc = xb + (size_t)row * CD;
    float o0 = fmaxf(d0 * inv * g[tid]       + b[tid],       0.0f);
    float o1 = fmaxf(d1 * inv * g[tid + 256] + b[tid + 256], 0.0f);
    float o2 = fmaxf(d2 * inv * g[tid + 512] + b[tid + 512], 0.0f);
    xo[tid] = f2bf(o0); xo[tid + 256] = f2bf(o1); xo[tid + 512] = f2bf(o2);
    xc[tid] = f2bf(v0); xc[tid + 256] = f2bf(v1); xc[tid + 512] = f2bf(v2);
}

// ---------------- Depthwise conv over T, full-T register blocking ----------------
template <int D>
__global__ __launch_bounds__(256)
void dwconv_kernel(const unsigned short* __restrict__ xn, const float* __restrict__ cw,
                   const float* __restrict__ cb, unsigned short* __restrict__ feat) {
    constexpr int KK = 2 * D + 1;
    int gid = blockIdx.x * 256 + threadIdx.x;     // 591*256 exact
    int bn = gid / 96;
    int cg = gid - bn * 96;
    int c0 = cg * 8;
    int b = bn / NTOK;
    size_t base = ((size_t)b * TFR * NTOK + (bn - b * NTOK)) * CD + c0;
    const size_t tstride = (size_t)NTOK * CD;

    short8 u[TFR];
#pragma unroll
    for (int t = 0; t < TFR; ++t)
        u[t] = *(const short8*)(xn + base + (size_t)t * tstride);

    float wgt[8][KK], bb[8];
#pragma unroll
    for (int q = 0; q < 8; ++q) {
        bb[q] = cb[c0 + q];
#pragma unroll
        for (int j = 0; j < KK; ++j) wgt[q][j] = cw[(c0 + q) * KK + j];
    }

#pragma unroll
    for (int t = 0; t < TFR; ++t) {
        float acc[8];
#pragma unroll
        for (int q = 0; q < 8; ++q) acc[q] = bb[q];
#pragma unroll
        for (int j = 0; j < KK; ++j) {
            int tj = t + j - D;
            if (tj < 0 || tj >= TFR) continue;   // compile-time (t,j unrolled)
#pragma unroll
            for (int q = 0; q < 8; ++q)
                acc[q] += bf2f((unsigned short)u[tj][q]) * wgt[q][j];
        }
        short8 o;
#pragma unroll
        for (int q = 0; q < 8; ++q) o[q] = (short)f2bf(acc[q]);
        *(short8*)(feat + base + (size_t)t * tstride) = o;
    }
}

// ---------------- weight transpose+convert: wt[n][k] = bf16(w[k][n]) ----------------
__global__ __launch_bounds__(256)
void wprep3_kernel(const float* __restrict__ w0, const float* __restrict__ w1,
                   const float* __restrict__ w2, unsigned short* __restrict__ t0,
                   unsigned short* __restrict__ t1, unsigned short* __restrict__ t2) {
    const float* w = blockIdx.y == 0 ? w0 : blockIdx.y == 1 ? w1 : w2;
    unsigned short* wt = blockIdx.y == 0 ? t0 : blockIdx.y == 1 ? t1 : t2;
    int gid = blockIdx.x * 256 + threadIdx.x;
    int n = gid / CD, k = gid - n * CD;
    wt[gid] = f2bf(w[(size_t)k * CD + n]);
}

// ---------------- fused = sum of shifted y_d (softmax weights pre-folded) ----------------
// fused[m][c]: c<256 past  -> y_d[m + d*NTOK][c] if t+d < T
//              c<512 future-> y_d[m - d*NTOK][c] if t-d >= 0
//              else  static-> y_d[m][c]
__global__ __launch_bounds__(256)
void fuse_kernel(const unsigned short* __restrict__ y1,
                 const unsigned short* __restrict__ y2,
                 const unsigned short* __restrict__ y3,
                 unsigned short* __restrict__ fused) {
    int gid = blockIdx.x * 256 + threadIdx.x;   // MROWS*96 threads, 9456 blocks exact
    int m = gid / 96;
    int kk = (gid - m * 96) * 8;
    int t = (m / NTOK) & 15;
    float vals[8] = {0.f, 0.f, 0.f, 0.f, 0.f, 0.f, 0.f, 0.f};
    const unsigned short* ys[3] = {y1, y2, y3};
#pragma unroll
    for (int d = 1; d <= 3; ++d) {
        int src; bool ok;
        if (kk < 256)      { src = m + d * NTOK; ok = (t + d) < TFR; }
        else if (kk < 512) { src = m - d * NTOK; ok = (t - d) >= 0; }
        else               { src = m;            ok = true; }
        if (ok) {
            short8 u = *(const short8*)(ys[d - 1] + (size_t)src * CD + kk);
#pragma unroll
            for (int e = 0; e < 8; ++e) vals[e] += bf2f((unsigned short)u[e]);
        }
    }
    short8 o;
#pragma unroll
    for (int e = 0; e < 8; ++e) o[e] = (short)f2bf(vals[e]);
    *(short8*)(fused + (size_t)m * CD + kk) = o;
}

// ---------------- 128x128-tile bf16 MFMA GEMM, double-buffered gl2lds staging ----------------
// EPI 0: gate  -> pure write bf16( wd * sigmoid(v) * xb )
// EPI 1: proj1 -> gelu -> bf16
// EPI 2: proj2 -> v + x -> fp32 out
// LDS layout (unpadded, required by global_load_lds): chunk q (0..7) covers
// rows q*16..q*16+15; lane i of the issuing wave lands at q*1024 + i*16 bytes,
// i.e. row q*16+i/4, shorts (i%4)*8 — matches the global address mapping.
// 2-phase pipeline: prefetch tile kt+32 into buf^1 BEFORE ds_read+MFMA of buf;
// the single __syncthreads (implicit vmcnt(0)+lgkmcnt(0) drain) per K-step
// both publishes the prefetch and protects buf reuse.
template <int EPI>
__global__ __launch_bounds__(256)
void gemm_kernel(const unsigned short* __restrict__ A,
                 const unsigned short* __restrict__ Bt,   // 768x768 bf16, N-major
                 const float* __restrict__ bias,
                 const unsigned short* __restrict__ xb,
                 const float* __restrict__ xf,
                 float* __restrict__ outf,
                 unsigned short* __restrict__ outh,
                 const float* __restrict__ fw,
                 int widx) {
    __shared__ unsigned short As[2][128 * 32];
    __shared__ unsigned short Bs[2][128 * 32];
    int tid  = threadIdx.x;
    int m0   = blockIdx.x * 128;   // m fastest -> concurrent blocks share B n-tile
    int n0   = blockIdx.y * 128;
    int wave = tid >> 6, lane = tid & 63;
    int wm   = (wave >> 1) * 64, wn = (wave & 1) * 64;
    int quad = lane >> 4, l16 = lane & 15;
    int r4   = lane >> 2;          // 0..15: row within chunk
    int ck   = (lane & 3) * 8;     // k-chunk (shorts)

    // staging addresses: chunk q = wave + h*4, row = q*16 + r4
    const size_t arow = (size_t)(m0 + wave * 16 + r4) * CD + ck;
    const size_t brow = (size_t)(n0 + wave * 16 + r4) * CD + ck;
    const size_t skip = (size_t)64 * CD;   // h=1 -> chunk q+4 -> row+64

    floatx4 acc[4][4];
#pragma unroll
    for (int i = 0; i < 4; ++i)
#pragma unroll
        for (int j = 0; j < 4; ++j) acc[i][j] = (floatx4){0.f, 0.f, 0.f, 0.f};

    // prologue: stage tile kt=0 into buffer 0
#pragma unroll
    for (int h = 0; h < 2; ++h) {
        gl2lds16(A  + arow + h * skip, &As[0][(wave + h * 4) * 512]);
        gl2lds16(Bt + brow + h * skip, &Bs[0][(wave + h * 4) * 512]);
    }
    __syncthreads();

    int buf = 0;
    for (int kt = 0; kt < CD; kt += 32) {
        if (kt + 32 < CD) {
#pragma unroll
            for (int h = 0; h < 2; ++h) {
                gl2lds16(A  + arow + h * skip + kt + 32, &As[buf ^ 1][(wave + h * 4) * 512]);
                gl2lds16(Bt + brow + h * skip + kt + 32, &Bs[buf ^ 1][(wave + h * 4) * 512]);
            }
        }
        short8 af[4], bfr[4];
#pragma unroll
        for (int i = 0; i < 4; ++i) af[i]  = *(const short8*)(&As[buf][(wm + i * 16 + l16) * 32 + quad * 8]);
#pragma unroll
        for (int j = 0; j < 4; ++j) bfr[j] = *(const short8*)(&Bs[buf][(wn + j * 16 + l16) * 32 + quad * 8]);
#pragma unroll
        for (int i = 0; i < 4; ++i)
#pragma unroll
            for (int j = 0; j < 4; ++j)
                acc[i][j] = __builtin_amdgcn_mfma_f32_16x16x32_bf16(af[i], bfr[j], acc[i][j], 0, 0, 0);
        __syncthreads();
        buf ^= 1;
    }

    float wd = 0.f;
    if (EPI == 0) {
        float f0 = fw[0], f1 = fw[1], f2 = fw[2];
        float mx = fmaxf(f0, fmaxf(f1, f2));
        float e0 = expf(f0 - mx), e1 = expf(f1 - mx), e2 = expf(f2 - mx);
        float inv = 1.f / (e0 + e1 + e2);
        wd = (widx == 0 ? e0 : widx == 1 ? e1 : e2) * inv;
    }

#pragma unroll
    for (int j = 0; j < 4; ++j) {
        int col = n0 + wn + j * 16 + l16;
        float bc = bias[col];
#pragma unroll
        for (int i = 0; i < 4; ++i) {
#pragma unroll
            for (int r = 0; r < 4; ++r) {
                int row = m0 + wm + i * 16 + quad * 4 + r;   // C/D: col=lane&15, row=quad*4+reg
                size_t idx = (size_t)row * CD + col;
                float v = acc[i][j][r] + bc;
                if (EPI == 0) {
                    float gte = 1.f / (1.f + expf(-v));
                    outh[idx] = f2bf(wd * gte * bf2f(xb[idx]));
                } else if (EPI == 1) {
                    float gl = 0.5f * v * (1.0f + erff(v * 0.70710678118f));
                    outh[idx] = f2bf(gl);
                } else {
                    outf[idx] = v + xf[idx];
                }
            }
        }
    }
}

extern "C" void kernel_launch(void* const* d_in, const int* in_sizes, int n_in,
                              void* d_out, int out_size, void* d_ws, size_t ws_size,
                              hipStream_t stream) {
    const float* x      = (const float*)d_in[0];
    const float* ln_g   = (const float*)d_in[1];
    const float* ln_b   = (const float*)d_in[2];
    const float* gate_w = (const float*)d_in[3];
    const float* gate_b = (const float*)d_in[4];
    const float* pw1    = (const float*)d_in[5];
    const float* pb1    = (const float*)d_in[6];
    const float* pw2    = (const float*)d_in[7];
    const float* pb2    = (const float*)d_in[8];
    const float* fw     = (const float*)d_in[9];
    const float* cw[3]  = {(const float*)d_in[11], (const float*)d_in[13], (const float*)d_in[15]};
    const float* cb[3]  = {(const float*)d_in[12], (const float*)d_in[14], (const float*)d_in[16]};

    char* ws = (char*)d_ws;
    const size_t SB = (size_t)MROWS * CD * 2;                   // 38,731,776
    unsigned short* gwt  = (unsigned short*)(ws + 0);
    unsigned short* p1t  = (unsigned short*)(ws + 1179648);
    unsigned short* p2t  = (unsigned short*)(ws + 2359296);
    unsigned short* xn   = (unsigned short*)(ws + 3538944);
    unsigned short* xb   = (unsigned short*)(ws + 3538944 + SB);
    unsigned short* feat = (unsigned short*)(ws + 3538944 + 2 * SB);
    unsigned short* y1   = (unsigned short*)(ws + 3538944 + 3 * SB);
    unsigned short* y2   = (unsigned short*)(ws + 3538944 + 4 * SB);
    unsigned short* y3   = (unsigned short*)(ws + 3538944 + 5 * SB);
    unsigned short* fused = feat;  // feat dead after last gate GEMM
    unsigned short* h1    = y1;    // y1 dead after fuse_kernel
    // total: 3,538,944 + 6*SB = 235,929,600 bytes

    dim3 wg(2304, 3);
    wprep3_kernel<<<wg, 256, 0, stream>>>(gate_w, pw1, pw2, gwt, p1t, p2t);
    ln_relu_kernel<<<MROWS, 256, 0, stream>>>(x, ln_g, ln_b, xn, xb);

    dim3 gg(197, 6);   // m-tiles fastest: concurrent blocks share one B n-tile
    dwconv_kernel<1><<<591, 256, 0, stream>>>(xn, cw[0], cb[0], feat);
    gemm_kernel<0><<<gg, 256, 0, stream>>>(feat, gwt, gate_b, xb, nullptr,
                                           nullptr, y1, fw, 0);
    dwconv_kernel<2><<<591, 256, 0, stream>>>(xn, cw[1], cb[1], feat);
    gemm_kernel<0><<<gg, 256, 0, stream>>>(feat, gwt, gate_b, xb, nullptr,
                                           nullptr, y2, fw, 1);
    dwconv_kernel<3><<<591, 256, 0, stream>>>(xn, cw[2], cb[2], feat);
    gemm_kernel<0><<<gg, 256, 0, stream>>>(feat, gwt, gate_b, xb, nullptr,
                                           nullptr, y3, fw, 2);

    fuse_kernel<<<9456, 256, 0, stream>>>(y1, y2, y3, fused);

    gemm_kernel<1><<<gg, 256, 0, stream>>>(fused, p1t, pb1, nullptr, nullptr,
                                           nullptr, h1, nullptr, 0);
    gemm_kernel<2><<<gg, 256, 0, stream>>>(h1, p2t, pb2, nullptr, x,
                                           (float*)d_out, nullptr, nullptr, 0);
}

// Round 2
// 611.844 us; speedup vs baseline: 1.1839x; 1.0695x over previous
//
#include <hip/hip_runtime.h>
#include <math.h>

// MultiScaleTransformerGSM on MI355X (gfx950).
// LN+ReLU(+bf16 x copy) -> per branch: dwconv -> gate GEMM -> fusion
// materialization -> proj1 GEMM -> proj2 GEMM + residual.
// R1: fused tensor materialized once; LDS double-buffer.
// R2: T4 counted-vmcnt pipeline: 3-buffer LDS rotation, raw s_barrier,
//     prefetch 2 tiles ahead, s_waitcnt vmcnt(4) steady-state (never 0
//     in the main loop), one barrier per K-step.

#define MROWS 25216   // B*T*N = 8*16*197
#define CD    768
#define NTOK  197
#define TFR   16

typedef __attribute__((ext_vector_type(8))) short short8;
typedef __attribute__((ext_vector_type(4))) float floatx4;
typedef unsigned int u32;

__device__ __forceinline__ unsigned short f2bf(float f) {
    union { float f; unsigned u; } v; v.f = f;
    unsigned r = v.u + 0x7FFFu + ((v.u >> 16) & 1u);
    return (unsigned short)(r >> 16);
}
__device__ __forceinline__ float bf2f(unsigned short h) {
    union { unsigned u; float f; } v; v.u = ((unsigned)h) << 16;
    return v.f;
}

// async global->LDS, 16B per lane; LDS dest = wave-uniform base + lane*16
__device__ __forceinline__ void gl2lds16(const void* g, void* l) {
    __builtin_amdgcn_global_load_lds(
        (__attribute__((address_space(1))) void*)(unsigned long long)g,
        (__attribute__((address_space(3))) void*)(u32)(unsigned long long)l,
        16, 0, 0);
}

// ---------------- LayerNorm + ReLU -> bf16 (also emits bf16 copy of x) ----------------
__global__ __launch_bounds__(256)
void ln_relu_kernel(const float* __restrict__ x, const float* __restrict__ g,
                    const float* __restrict__ b, unsigned short* __restrict__ xn,
                    unsigned short* __restrict__ xb) {
    int row = blockIdx.x;
    int tid = threadIdx.x;
    const float* xr = x + (size_t)row * CD;
    float v0 = xr[tid], v1 = xr[tid + 256], v2 = xr[tid + 512];
    float s = v0 + v1 + v2;
    __shared__ float red[8];
#pragma unroll
    for (int off = 32; off; off >>= 1) s += __shfl_down(s, off, 64);
    int lane = tid & 63, w = tid >> 6;
    if (lane == 0) red[w] = s;
    __syncthreads();
    float mean = (red[0] + red[1] + red[2] + red[3]) * (1.0f / CD);
    float d0 = v0 - mean, d1 = v1 - mean, d2 = v2 - mean;
    float s2 = d0 * d0 + d1 * d1 + d2 * d2;
#pragma unroll
    for (int off = 32; off; off >>= 1) s2 += __shfl_down(s2, off, 64);
    if (lane == 0) red[4 + w] = s2;
    __syncthreads();
    float var = (red[4] + red[5] + red[6] + red[7]) * (1.0f / CD);
    float inv = rsqrtf(var + 1e-5f);
    unsigned short* xo = xn + (size_t)row * CD;
    unsigned short* xc = xb + (size_t)row * CD;
    float o0 = fmaxf(d0 * inv * g[tid]       + b[tid],       0.0f);
    float o1 = fmaxf(d1 * inv * g[tid + 256] + b[tid + 256], 0.0f);
    float o2 = fmaxf(d2 * inv * g[tid + 512] + b[tid + 512], 0.0f);
    xo[tid] = f2bf(o0); xo[tid + 256] = f2bf(o1); xo[tid + 512] = f2bf(o2);
    xc[tid] = f2bf(v0); xc[tid + 256] = f2bf(v1); xc[tid + 512] = f2bf(v2);
}

// ---------------- Depthwise conv over T, full-T register blocking ----------------
template <int D>
__global__ __launch_bounds__(256)
void dwconv_kernel(const unsigned short* __restrict__ xn, const float* __restrict__ cw,
                   const float* __restrict__ cb, unsigned short* __restrict__ feat) {
    constexpr int KK = 2 * D + 1;
    int gid = blockIdx.x * 256 + threadIdx.x;     // 591*256 exact
    int bn = gid / 96;
    int cg = gid - bn * 96;
    int c0 = cg * 8;
    int b = bn / NTOK;
    size_t base = ((size_t)b * TFR * NTOK + (bn - b * NTOK)) * CD + c0;
    const size_t tstride = (size_t)NTOK * CD;

    short8 u[TFR];
#pragma unroll
    for (int t = 0; t < TFR; ++t)
        u[t] = *(const short8*)(xn + base + (size_t)t * tstride);

    float wgt[8][KK], bb[8];
#pragma unroll
    for (int q = 0; q < 8; ++q) {
        bb[q] = cb[c0 + q];
#pragma unroll
        for (int j = 0; j < KK; ++j) wgt[q][j] = cw[(c0 + q) * KK + j];
    }

#pragma unroll
    for (int t = 0; t < TFR; ++t) {
        float acc[8];
#pragma unroll
        for (int q = 0; q < 8; ++q) acc[q] = bb[q];
#pragma unroll
        for (int j = 0; j < KK; ++j) {
            int tj = t + j - D;
            if (tj < 0 || tj >= TFR) continue;   // compile-time (t,j unrolled)
#pragma unroll
            for (int q = 0; q < 8; ++q)
                acc[q] += bf2f((unsigned short)u[tj][q]) * wgt[q][j];
        }
        short8 o;
#pragma unroll
        for (int q = 0; q < 8; ++q) o[q] = (short)f2bf(acc[q]);
        *(short8*)(feat + base + (size_t)t * tstride) = o;
    }
}

// ---------------- weight transpose+convert: wt[n][k] = bf16(w[k][n]) ----------------
__global__ __launch_bounds__(256)
void wprep3_kernel(const float* __restrict__ w0, const float* __restrict__ w1,
                   const float* __restrict__ w2, unsigned short* __restrict__ t0,
                   unsigned short* __restrict__ t1, unsigned short* __restrict__ t2) {
    const float* w = blockIdx.y == 0 ? w0 : blockIdx.y == 1 ? w1 : w2;
    unsigned short* wt = blockIdx.y == 0 ? t0 : blockIdx.y == 1 ? t1 : t2;
    int gid = blockIdx.x * 256 + threadIdx.x;
    int n = gid / CD, k = gid - n * CD;
    wt[gid] = f2bf(w[(size_t)k * CD + n]);
}

// ---------------- fused = sum of shifted y_d (softmax weights pre-folded) ----------------
__global__ __launch_bounds__(256)
void fuse_kernel(const unsigned short* __restrict__ y1,
                 const unsigned short* __restrict__ y2,
                 const unsigned short* __restrict__ y3,
                 unsigned short* __restrict__ fused) {
    int gid = blockIdx.x * 256 + threadIdx.x;   // MROWS*96 threads, 9456 blocks exact
    int m = gid / 96;
    int kk = (gid - m * 96) * 8;
    int t = (m / NTOK) & 15;
    float vals[8] = {0.f, 0.f, 0.f, 0.f, 0.f, 0.f, 0.f, 0.f};
    const unsigned short* ys[3] = {y1, y2, y3};
#pragma unroll
    for (int d = 1; d <= 3; ++d) {
        int src; bool ok;
        if (kk < 256)      { src = m + d * NTOK; ok = (t + d) < TFR; }
        else if (kk < 512) { src = m - d * NTOK; ok = (t - d) >= 0; }
        else               { src = m;            ok = true; }
        if (ok) {
            short8 u = *(const short8*)(ys[d - 1] + (size_t)src * CD + kk);
#pragma unroll
            for (int e = 0; e < 8; ++e) vals[e] += bf2f((unsigned short)u[e]);
        }
    }
    short8 o;
#pragma unroll
    for (int e = 0; e < 8; ++e) o[e] = (short)f2bf(vals[e]);
    *(short8*)(fused + (size_t)m * CD + kk) = o;
}

// ---------------- 128x128-tile bf16 MFMA GEMM, 3-deep counted-vmcnt pipeline ----------------
// EPI 0: gate  -> pure write bf16( wd * sigmoid(v) * xb )
// EPI 1: proj1 -> gelu -> bf16
// EPI 2: proj2 -> v + x -> fp32 out
// LDS layout (unpadded, required by global_load_lds): chunk q (0..7) covers
// rows q*16..q*16+15; lane i of the issuing wave lands at q*1024 + i*16 bytes.
// Pipeline (T4): 3 LDS buffers; prologue stages tiles 0,1; iter t waits
// vmcnt(4) (tile t landed, tile t+1 in flight), s_barrier publishes across
// waves, then issues tile t+2 into buf[(t+2)%3] (== buffer read at iter t-1,
// proven retired: every wave passed this barrier only after its iter-(t-1)
// ds_reads drained via lgkmcnt before the MFMAs). sched_barrier(0) after the
// barrier pins source order (rule #18 analog). Last iter peeled w/ vmcnt(0).
template <int EPI>
__global__ __launch_bounds__(256)
void gemm_kernel(const unsigned short* __restrict__ A,
                 const unsigned short* __restrict__ Bt,   // 768x768 bf16, N-major
                 const float* __restrict__ bias,
                 const unsigned short* __restrict__ xb,
                 const float* __restrict__ xf,
                 float* __restrict__ outf,
                 unsigned short* __restrict__ outh,
                 const float* __restrict__ fw,
                 int widx) {
    __shared__ unsigned short As[3][128 * 32];
    __shared__ unsigned short Bs[3][128 * 32];
    int tid  = threadIdx.x;
    int m0   = blockIdx.x * 128;   // m fastest -> concurrent blocks share B n-tile
    int n0   = blockIdx.y * 128;
    int wave = tid >> 6, lane = tid & 63;
    int wm   = (wave >> 1) * 64, wn = (wave & 1) * 64;
    int quad = lane >> 4, l16 = lane & 15;
    int r4   = lane >> 2;          // 0..15: row within chunk
    int ck   = (lane & 3) * 8;     // k-chunk (shorts)

    // staging addresses: chunk q = wave + h*4, row = q*16 + r4
    const size_t arow = (size_t)(m0 + wave * 16 + r4) * CD + ck;
    const size_t brow = (size_t)(n0 + wave * 16 + r4) * CD + ck;
    const size_t skip = (size_t)64 * CD;   // h=1 -> chunk q+4 -> row+64

    floatx4 acc[4][4];
#pragma unroll
    for (int i = 0; i < 4; ++i)
#pragma unroll
        for (int j = 0; j < 4; ++j) acc[i][j] = (floatx4){0.f, 0.f, 0.f, 0.f};

    auto stage = [&](int t, int b) {
        const size_t ko = (size_t)t * 32;
#pragma unroll
        for (int h = 0; h < 2; ++h) {
            gl2lds16(A  + arow + h * skip + ko, &As[b][(wave + h * 4) * 512]);
            gl2lds16(Bt + brow + h * skip + ko, &Bs[b][(wave + h * 4) * 512]);
        }
    };
    auto compute = [&](int b) {
        short8 af[4], bfr[4];
#pragma unroll
        for (int i = 0; i < 4; ++i) af[i]  = *(const short8*)(&As[b][(wm + i * 16 + l16) * 32 + quad * 8]);
#pragma unroll
        for (int j = 0; j < 4; ++j) bfr[j] = *(const short8*)(&Bs[b][(wn + j * 16 + l16) * 32 + quad * 8]);
#pragma unroll
        for (int i = 0; i < 4; ++i)
#pragma unroll
            for (int j = 0; j < 4; ++j)
                acc[i][j] = __builtin_amdgcn_mfma_f32_16x16x32_bf16(af[i], bfr[j], acc[i][j], 0, 0, 0);
    };

    constexpr int NT = CD / 32;    // 24 K-steps
    stage(0, 0);
    stage(1, 1);
    for (int t = 0; t < NT - 1; ++t) {
        asm volatile("s_waitcnt vmcnt(4)" ::: "memory");   // tile t landed; t+1 in flight
        __builtin_amdgcn_s_barrier();
        __builtin_amdgcn_sched_barrier(0);
        if (t + 2 < NT) stage(t + 2, (t + 2) % 3);
        compute(t % 3);
    }
    asm volatile("s_waitcnt vmcnt(0)" ::: "memory");       // last tile
    __builtin_amdgcn_s_barrier();
    __builtin_amdgcn_sched_barrier(0);
    compute((NT - 1) % 3);

    float wd = 0.f;
    if (EPI == 0) {
        float f0 = fw[0], f1 = fw[1], f2 = fw[2];
        float mx = fmaxf(f0, fmaxf(f1, f2));
        float e0 = expf(f0 - mx), e1 = expf(f1 - mx), e2 = expf(f2 - mx);
        float inv = 1.f / (e0 + e1 + e2);
        wd = (widx == 0 ? e0 : widx == 1 ? e1 : e2) * inv;
    }

#pragma unroll
    for (int j = 0; j < 4; ++j) {
        int col = n0 + wn + j * 16 + l16;
        float bc = bias[col];
#pragma unroll
        for (int i = 0; i < 4; ++i) {
#pragma unroll
            for (int r = 0; r < 4; ++r) {
                int row = m0 + wm + i * 16 + quad * 4 + r;   // C/D: col=lane&15, row=quad*4+reg
                size_t idx = (size_t)row * CD + col;
                float v = acc[i][j][r] + bc;
                if (EPI == 0) {
                    float gte = 1.f / (1.f + expf(-v));
                    outh[idx] = f2bf(wd * gte * bf2f(xb[idx]));
                } else if (EPI == 1) {
                    float gl = 0.5f * v * (1.0f + erff(v * 0.70710678118f));
                    outh[idx] = f2bf(gl);
                } else {
                    outf[idx] = v + xf[idx];
                }
            }
        }
    }
}

extern "C" void kernel_launch(void* const* d_in, const int* in_sizes, int n_in,
                              void* d_out, int out_size, void* d_ws, size_t ws_size,
                              hipStream_t stream) {
    const float* x      = (const float*)d_in[0];
    const float* ln_g   = (const float*)d_in[1];
    const float* ln_b   = (const float*)d_in[2];
    const float* gate_w = (const float*)d_in[3];
    const float* gate_b = (const float*)d_in[4];
    const float* pw1    = (const float*)d_in[5];
    const float* pb1    = (const float*)d_in[6];
    const float* pw2    = (const float*)d_in[7];
    const float* pb2    = (const float*)d_in[8];
    const float* fw     = (const float*)d_in[9];
    const float* cw[3]  = {(const float*)d_in[11], (const float*)d_in[13], (const float*)d_in[15]};
    const float* cb[3]  = {(const float*)d_in[12], (const float*)d_in[14], (const float*)d_in[16]};

    char* ws = (char*)d_ws;
    const size_t SB = (size_t)MROWS * CD * 2;                   // 38,731,776
    unsigned short* gwt  = (unsigned short*)(ws + 0);
    unsigned short* p1t  = (unsigned short*)(ws + 1179648);
    unsigned short* p2t  = (unsigned short*)(ws + 2359296);
    unsigned short* xn   = (unsigned short*)(ws + 3538944);
    unsigned short* xb   = (unsigned short*)(ws + 3538944 + SB);
    unsigned short* feat = (unsigned short*)(ws + 3538944 + 2 * SB);
    unsigned short* y1   = (unsigned short*)(ws + 3538944 + 3 * SB);
    unsigned short* y2   = (unsigned short*)(ws + 3538944 + 4 * SB);
    unsigned short* y3   = (unsigned short*)(ws + 3538944 + 5 * SB);
    unsigned short* fused = feat;  // feat dead after last gate GEMM
    unsigned short* h1    = y1;    // y1 dead after fuse_kernel
    // total: 3,538,944 + 6*SB = 235,929,600 bytes

    dim3 wg(2304, 3);
    wprep3_kernel<<<wg, 256, 0, stream>>>(gate_w, pw1, pw2, gwt, p1t, p2t);
    ln_relu_kernel<<<MROWS, 256, 0, stream>>>(x, ln_g, ln_b, xn, xb);

    dim3 gg(197, 6);   // m-tiles fastest: concurrent blocks share one B n-tile
    dwconv_kernel<1><<<591, 256, 0, stream>>>(xn, cw[0], cb[0], feat);
    gemm_kernel<0><<<gg, 256, 0, stream>>>(feat, gwt, gate_b, xb, nullptr,
                                           nullptr, y1, fw, 0);
    dwconv_kernel<2><<<591, 256, 0, stream>>>(xn, cw[1], cb[1], feat);
    gemm_kernel<0><<<gg, 256, 0, stream>>>(feat, gwt, gate_b, xb, nullptr,
                                           nullptr, y2, fw, 1);
    dwconv_kernel<3><<<591, 256, 0, stream>>>(xn, cw[2], cb[2], feat);
    gemm_kernel<0><<<gg, 256, 0, stream>>>(feat, gwt, gate_b, xb, nullptr,
                                           nullptr, y3, fw, 2);

    fuse_kernel<<<9456, 256, 0, stream>>>(y1, y2, y3, fused);

    gemm_kernel<1><<<gg, 256, 0, stream>>>(fused, p1t, pb1, nullptr, nullptr,
                                           nullptr, h1, nullptr, 0);
    gemm_kernel<2><<<gg, 256, 0, stream>>>(h1, p2t, pb2, nullptr, x,
                                           (float*)d_out, nullptr, nullptr, 0);
}

// Round 3
// 591.304 us; speedup vs baseline: 1.2250x; 1.0347x over previous
//
#include <hip/hip_runtime.h>
#include <math.h>

// MultiScaleTransformerGSM on MI355X (gfx950).
// LN+ReLU(+bf16 x copy) -> per branch: dwconv -> gate GEMM -> fusion
// materialization -> proj1 GEMM -> proj2 GEMM + residual.
// R1: fused tensor materialized once; LDS double-buffer.
// R2: counted-vmcnt pipeline (3 buffers, depth-2, vmcnt(4)).
// R3: (a) T2 bank-conflict swizzle done rule-#21 style: linear LDS dest,
//         pre-swizzled GLOBAL source k-slot (slot ^= (row>>1)&3), same XOR
//         on the ds_read address — 8-way conflict -> 2-way (free).
//     (b) depth-3 prefetch, 4 LDS buffers, vmcnt(8) steady state.

#define MROWS 25216   // B*T*N = 8*16*197
#define CD    768
#define NTOK  197
#define TFR   16

typedef __attribute__((ext_vector_type(8))) short short8;
typedef __attribute__((ext_vector_type(4))) float floatx4;
typedef unsigned int u32;

__device__ __forceinline__ unsigned short f2bf(float f) {
    union { float f; unsigned u; } v; v.f = f;
    unsigned r = v.u + 0x7FFFu + ((v.u >> 16) & 1u);
    return (unsigned short)(r >> 16);
}
__device__ __forceinline__ float bf2f(unsigned short h) {
    union { unsigned u; float f; } v; v.u = ((unsigned)h) << 16;
    return v.f;
}

// async global->LDS, 16B per lane; LDS dest = wave-uniform base + lane*16
__device__ __forceinline__ void gl2lds16(const void* g, void* l) {
    __builtin_amdgcn_global_load_lds(
        (__attribute__((address_space(1))) void*)(unsigned long long)g,
        (__attribute__((address_space(3))) void*)(u32)(unsigned long long)l,
        16, 0, 0);
}

// ---------------- LayerNorm + ReLU -> bf16 (also emits bf16 copy of x) ----------------
__global__ __launch_bounds__(256)
void ln_relu_kernel(const float* __restrict__ x, const float* __restrict__ g,
                    const float* __restrict__ b, unsigned short* __restrict__ xn,
                    unsigned short* __restrict__ xb) {
    int row = blockIdx.x;
    int tid = threadIdx.x;
    const float* xr = x + (size_t)row * CD;
    float v0 = xr[tid], v1 = xr[tid + 256], v2 = xr[tid + 512];
    float s = v0 + v1 + v2;
    __shared__ float red[8];
#pragma unroll
    for (int off = 32; off; off >>= 1) s += __shfl_down(s, off, 64);
    int lane = tid & 63, w = tid >> 6;
    if (lane == 0) red[w] = s;
    __syncthreads();
    float mean = (red[0] + red[1] + red[2] + red[3]) * (1.0f / CD);
    float d0 = v0 - mean, d1 = v1 - mean, d2 = v2 - mean;
    float s2 = d0 * d0 + d1 * d1 + d2 * d2;
#pragma unroll
    for (int off = 32; off; off >>= 1) s2 += __shfl_down(s2, off, 64);
    if (lane == 0) red[4 + w] = s2;
    __syncthreads();
    float var = (red[4] + red[5] + red[6] + red[7]) * (1.0f / CD);
    float inv = rsqrtf(var + 1e-5f);
    unsigned short* xo = xn + (size_t)row * CD;
    unsigned short* xc = xb + (size_t)row * CD;
    float o0 = fmaxf(d0 * inv * g[tid]       + b[tid],       0.0f);
    float o1 = fmaxf(d1 * inv * g[tid + 256] + b[tid + 256], 0.0f);
    float o2 = fmaxf(d2 * inv * g[tid + 512] + b[tid + 512], 0.0f);
    xo[tid] = f2bf(o0); xo[tid + 256] = f2bf(o1); xo[tid + 512] = f2bf(o2);
    xc[tid] = f2bf(v0); xc[tid + 256] = f2bf(v1); xc[tid + 512] = f2bf(v2);
}

// ---------------- Depthwise conv over T, full-T register blocking ----------------
template <int D>
__global__ __launch_bounds__(256)
void dwconv_kernel(const unsigned short* __restrict__ xn, const float* __restrict__ cw,
                   const float* __restrict__ cb, unsigned short* __restrict__ feat) {
    constexpr int KK = 2 * D + 1;
    int gid = blockIdx.x * 256 + threadIdx.x;     // 591*256 exact
    int bn = gid / 96;
    int cg = gid - bn * 96;
    int c0 = cg * 8;
    int b = bn / NTOK;
    size_t base = ((size_t)b * TFR * NTOK + (bn - b * NTOK)) * CD + c0;
    const size_t tstride = (size_t)NTOK * CD;

    short8 u[TFR];
#pragma unroll
    for (int t = 0; t < TFR; ++t)
        u[t] = *(const short8*)(xn + base + (size_t)t * tstride);

    float wgt[8][KK], bb[8];
#pragma unroll
    for (int q = 0; q < 8; ++q) {
        bb[q] = cb[c0 + q];
#pragma unroll
        for (int j = 0; j < KK; ++j) wgt[q][j] = cw[(c0 + q) * KK + j];
    }

#pragma unroll
    for (int t = 0; t < TFR; ++t) {
        float acc[8];
#pragma unroll
        for (int q = 0; q < 8; ++q) acc[q] = bb[q];
#pragma unroll
        for (int j = 0; j < KK; ++j) {
            int tj = t + j - D;
            if (tj < 0 || tj >= TFR) continue;   // compile-time (t,j unrolled)
#pragma unroll
            for (int q = 0; q < 8; ++q)
                acc[q] += bf2f((unsigned short)u[tj][q]) * wgt[q][j];
        }
        short8 o;
#pragma unroll
        for (int q = 0; q < 8; ++q) o[q] = (short)f2bf(acc[q]);
        *(short8*)(feat + base + (size_t)t * tstride) = o;
    }
}

// ---------------- weight transpose+convert: wt[n][k] = bf16(w[k][n]) ----------------
__global__ __launch_bounds__(256)
void wprep3_kernel(const float* __restrict__ w0, const float* __restrict__ w1,
                   const float* __restrict__ w2, unsigned short* __restrict__ t0,
                   unsigned short* __restrict__ t1, unsigned short* __restrict__ t2) {
    const float* w = blockIdx.y == 0 ? w0 : blockIdx.y == 1 ? w1 : w2;
    unsigned short* wt = blockIdx.y == 0 ? t0 : blockIdx.y == 1 ? t1 : t2;
    int gid = blockIdx.x * 256 + threadIdx.x;
    int n = gid / CD, k = gid - n * CD;
    wt[gid] = f2bf(w[(size_t)k * CD + n]);
}

// ---------------- fused = sum of shifted y_d (softmax weights pre-folded) ----------------
__global__ __launch_bounds__(256)
void fuse_kernel(const unsigned short* __restrict__ y1,
                 const unsigned short* __restrict__ y2,
                 const unsigned short* __restrict__ y3,
                 unsigned short* __restrict__ fused) {
    int gid = blockIdx.x * 256 + threadIdx.x;   // MROWS*96 threads, 9456 blocks exact
    int m = gid / 96;
    int kk = (gid - m * 96) * 8;
    int t = (m / NTOK) & 15;
    float vals[8] = {0.f, 0.f, 0.f, 0.f, 0.f, 0.f, 0.f, 0.f};
    const unsigned short* ys[3] = {y1, y2, y3};
#pragma unroll
    for (int d = 1; d <= 3; ++d) {
        int src; bool ok;
        if (kk < 256)      { src = m + d * NTOK; ok = (t + d) < TFR; }
        else if (kk < 512) { src = m - d * NTOK; ok = (t - d) >= 0; }
        else               { src = m;            ok = true; }
        if (ok) {
            short8 u = *(const short8*)(ys[d - 1] + (size_t)src * CD + kk);
#pragma unroll
            for (int e = 0; e < 8; ++e) vals[e] += bf2f((unsigned short)u[e]);
        }
    }
    short8 o;
#pragma unroll
    for (int e = 0; e < 8; ++e) o[e] = (short)f2bf(vals[e]);
    *(short8*)(fused + (size_t)m * CD + kk) = o;
}

// ---------------- 128x128-tile bf16 MFMA GEMM, 4-deep counted-vmcnt pipeline ----------------
// EPI 0: gate  -> pure write bf16( wd * sigmoid(v) * xb )
// EPI 1: proj1 -> gelu -> bf16
// EPI 2: proj2 -> v + x -> fp32 out
// LDS: linear [128 rows][4 slots of 16B] per buffer (global_load_lds writes
// base+lane*16). Bank-conflict swizzle (rule #21, both-sides): physical slot p
// of row r holds LOGICAL k-slot p ^ ((r>>1)&3); achieved by swizzling the
// GLOBAL source address at stage time, and XOR-ing the ds_read slot the same
// way. 16 lanes then cover 8 distinct 4-bank groups (2 lanes/bank = free)
// instead of 2 (8-way conflict, was 3.6M conflict cycles/dispatch).
// Pipeline: 4 buffers, stage 3 tiles ahead; iter t waits vmcnt(8) (12 loads
// in flight -> oldest 4 = tile t retired; vmem retires in issue order),
// s_barrier publishes across waves, sched_barrier(0) pins order, stage(t+3)
// overwrites the buffer whose reads all waves retired before this barrier.
// Tail peeled with vmcnt(4), vmcnt(0).
template <int EPI>
__global__ __launch_bounds__(256)
void gemm_kernel(const unsigned short* __restrict__ A,
                 const unsigned short* __restrict__ Bt,   // 768x768 bf16, N-major
                 const float* __restrict__ bias,
                 const unsigned short* __restrict__ xb,
                 const float* __restrict__ xf,
                 float* __restrict__ outf,
                 unsigned short* __restrict__ outh,
                 const float* __restrict__ fw,
                 int widx) {
    __shared__ unsigned short As[4][128 * 32];
    __shared__ unsigned short Bs[4][128 * 32];
    int tid  = threadIdx.x;
    int m0   = blockIdx.x * 128;   // m fastest -> concurrent blocks share B n-tile
    int n0   = blockIdx.y * 128;
    int wave = tid >> 6, lane = tid & 63;
    int wm   = (wave >> 1) * 64, wn = (wave & 1) * 64;
    int quad = lane >> 4, l16 = lane & 15;
    int r4   = lane >> 2;          // 0..15: row within chunk
    // swizzled k-slot for staging: physical slot (lane&3) of row ..+r4 pulls
    // logical slot (lane&3) ^ ((r4>>1)&3)   [ (row>>1)&3 == (r4>>1)&3 ]
    int ckx  = (((lane & 3) ^ ((lane >> 3) & 3)) * 8);
    // swizzled slot for fragment reads: logical slot 'quad' of row 16a+l16
    // lives at physical slot quad ^ ((l16>>1)&3)
    int rdsl = (quad ^ ((l16 >> 1) & 3)) * 8;

    const size_t arow = (size_t)(m0 + wave * 16 + r4) * CD + ckx;
    const size_t brow = (size_t)(n0 + wave * 16 + r4) * CD + ckx;
    const size_t skip = (size_t)64 * CD;   // h=1 -> chunk q+4 -> row+64

    floatx4 acc[4][4];
#pragma unroll
    for (int i = 0; i < 4; ++i)
#pragma unroll
        for (int j = 0; j < 4; ++j) acc[i][j] = (floatx4){0.f, 0.f, 0.f, 0.f};

    auto stage = [&](int t, int b) {
        const size_t ko = (size_t)t * 32;
#pragma unroll
        for (int h = 0; h < 2; ++h) {
            gl2lds16(A  + arow + h * skip + ko, &As[b][(wave + h * 4) * 512]);
            gl2lds16(Bt + brow + h * skip + ko, &Bs[b][(wave + h * 4) * 512]);
        }
    };
    auto compute = [&](int b) {
        short8 af[4], bfr[4];
#pragma unroll
        for (int i = 0; i < 4; ++i) af[i]  = *(const short8*)(&As[b][(wm + i * 16 + l16) * 32 + rdsl]);
#pragma unroll
        for (int j = 0; j < 4; ++j) bfr[j] = *(const short8*)(&Bs[b][(wn + j * 16 + l16) * 32 + rdsl]);
#pragma unroll
        for (int i = 0; i < 4; ++i)
#pragma unroll
            for (int j = 0; j < 4; ++j)
                acc[i][j] = __builtin_amdgcn_mfma_f32_16x16x32_bf16(af[i], bfr[j], acc[i][j], 0, 0, 0);
    };

    constexpr int NT = CD / 32;    // 24 K-steps
    stage(0, 0);
    stage(1, 1);
    stage(2, 2);
    for (int t = 0; t < NT - 2; ++t) {
        asm volatile("s_waitcnt vmcnt(8)" ::: "memory");   // tile t landed; t+1,t+2 in flight
        __builtin_amdgcn_s_barrier();
        __builtin_amdgcn_sched_barrier(0);
        if (t + 3 < NT) stage(t + 3, (t + 3) & 3);
        compute(t & 3);
    }
    asm volatile("s_waitcnt vmcnt(4)" ::: "memory");       // tile NT-2 landed
    __builtin_amdgcn_s_barrier();
    __builtin_amdgcn_sched_barrier(0);
    compute((NT - 2) & 3);
    asm volatile("s_waitcnt vmcnt(0)" ::: "memory");       // tile NT-1 landed
    __builtin_amdgcn_s_barrier();
    __builtin_amdgcn_sched_barrier(0);
    compute((NT - 1) & 3);

    float wd = 0.f;
    if (EPI == 0) {
        float f0 = fw[0], f1 = fw[1], f2 = fw[2];
        float mx = fmaxf(f0, fmaxf(f1, f2));
        float e0 = expf(f0 - mx), e1 = expf(f1 - mx), e2 = expf(f2 - mx);
        float inv = 1.f / (e0 + e1 + e2);
        wd = (widx == 0 ? e0 : widx == 1 ? e1 : e2) * inv;
    }

#pragma unroll
    for (int j = 0; j < 4; ++j) {
        int col = n0 + wn + j * 16 + l16;
        float bc = bias[col];
#pragma unroll
        for (int i = 0; i < 4; ++i) {
#pragma unroll
            for (int r = 0; r < 4; ++r) {
                int row = m0 + wm + i * 16 + quad * 4 + r;   // C/D: col=lane&15, row=quad*4+reg
                size_t idx = (size_t)row * CD + col;
                float v = acc[i][j][r] + bc;
                if (EPI == 0) {
                    float gte = 1.f / (1.f + expf(-v));
                    outh[idx] = f2bf(wd * gte * bf2f(xb[idx]));
                } else if (EPI == 1) {
                    float gl = 0.5f * v * (1.0f + erff(v * 0.70710678118f));
                    outh[idx] = f2bf(gl);
                } else {
                    outf[idx] = v + xf[idx];
                }
            }
        }
    }
}

extern "C" void kernel_launch(void* const* d_in, const int* in_sizes, int n_in,
                              void* d_out, int out_size, void* d_ws, size_t ws_size,
                              hipStream_t stream) {
    const float* x      = (const float*)d_in[0];
    const float* ln_g   = (const float*)d_in[1];
    const float* ln_b   = (const float*)d_in[2];
    const float* gate_w = (const float*)d_in[3];
    const float* gate_b = (const float*)d_in[4];
    const float* pw1    = (const float*)d_in[5];
    const float* pb1    = (const float*)d_in[6];
    const float* pw2    = (const float*)d_in[7];
    const float* pb2    = (const float*)d_in[8];
    const float* fw     = (const float*)d_in[9];
    const float* cw[3]  = {(const float*)d_in[11], (const float*)d_in[13], (const float*)d_in[15]};
    const float* cb[3]  = {(const float*)d_in[12], (const float*)d_in[14], (const float*)d_in[16]};

    char* ws = (char*)d_ws;
    const size_t SB = (size_t)MROWS * CD * 2;                   // 38,731,776
    unsigned short* gwt  = (unsigned short*)(ws + 0);
    unsigned short* p1t  = (unsigned short*)(ws + 1179648);
    unsigned short* p2t  = (unsigned short*)(ws + 2359296);
    unsigned short* xn   = (unsigned short*)(ws + 3538944);
    unsigned short* xb   = (unsigned short*)(ws + 3538944 + SB);
    unsigned short* feat = (unsigned short*)(ws + 3538944 + 2 * SB);
    unsigned short* y1   = (unsigned short*)(ws + 3538944 + 3 * SB);
    unsigned short* y2   = (unsigned short*)(ws + 3538944 + 4 * SB);
    unsigned short* y3   = (unsigned short*)(ws + 3538944 + 5 * SB);
    unsigned short* fused = feat;  // feat dead after last gate GEMM
    unsigned short* h1    = y1;    // y1 dead after fuse_kernel
    // total: 3,538,944 + 6*SB = 235,929,600 bytes

    dim3 wg(2304, 3);
    wprep3_kernel<<<wg, 256, 0, stream>>>(gate_w, pw1, pw2, gwt, p1t, p2t);
    ln_relu_kernel<<<MROWS, 256, 0, stream>>>(x, ln_g, ln_b, xn, xb);

    dim3 gg(197, 6);   // m-tiles fastest: concurrent blocks share one B n-tile
    dwconv_kernel<1><<<591, 256, 0, stream>>>(xn, cw[0], cb[0], feat);
    gemm_kernel<0><<<gg, 256, 0, stream>>>(feat, gwt, gate_b, xb, nullptr,
                                           nullptr, y1, fw, 0);
    dwconv_kernel<2><<<591, 256, 0, stream>>>(xn, cw[1], cb[1], feat);
    gemm_kernel<0><<<gg, 256, 0, stream>>>(feat, gwt, gate_b, xb, nullptr,
                                           nullptr, y2, fw, 1);
    dwconv_kernel<3><<<591, 256, 0, stream>>>(xn, cw[2], cb[2], feat);
    gemm_kernel<0><<<gg, 256, 0, stream>>>(feat, gwt, gate_b, xb, nullptr,
                                           nullptr, y3, fw, 2);

    fuse_kernel<<<9456, 256, 0, stream>>>(y1, y2, y3, fused);

    gemm_kernel<1><<<gg, 256, 0, stream>>>(fused, p1t, pb1, nullptr, nullptr,
                                           nullptr, h1, nullptr, 0);
    gemm_kernel<2><<<gg, 256, 0, stream>>>(h1, p2t, pb2, nullptr, x,
                                           (float*)d_out, nullptr, nullptr, 0);
}

// Round 4
// 554.914 us; speedup vs baseline: 1.3053x; 1.0656x over previous
//
#include <hip/hip_runtime.h>
#include <math.h>

// MultiScaleTransformerGSM on MI355X (gfx950).
// LN+ReLU(+bf16 x copy) -> merged dwconv(3 branches) -> 3x gate GEMM ->
// fusion materialization -> proj1 GEMM -> proj2 GEMM + residual.
// R1: fused tensor materialized once; LDS double-buffer.
// R2: counted-vmcnt pipeline (3 buffers, depth-2, vmcnt(4)).
// R3: global-source bank-conflict swizzle (conflicts -> 0); depth-3 vmcnt(8).
// R4: (a) coalesced epilogue via LDS f32 bounce (2 half-passes) -- kills the
//         2B-scattered store/load HBM amplification (WRITE ~2x ideal before);
//     (b) 3 dwconvs merged into one dispatch; workspace aliasing tightened
//         (197MB total).  K-loop kept byte-identical to R3 to isolate (a).

#define MROWS 25216   // B*T*N = 8*16*197
#define CD    768
#define NTOK  197
#define TFR   16

typedef __attribute__((ext_vector_type(8))) short short8;
typedef __attribute__((ext_vector_type(4))) float floatx4;
typedef unsigned int u32;

__device__ __forceinline__ unsigned short f2bf(float f) {
    union { float f; unsigned u; } v; v.f = f;
    unsigned r = v.u + 0x7FFFu + ((v.u >> 16) & 1u);
    return (unsigned short)(r >> 16);
}
__device__ __forceinline__ float bf2f(unsigned short h) {
    union { unsigned u; float f; } v; v.u = ((unsigned)h) << 16;
    return v.f;
}

// async global->LDS, 16B per lane; LDS dest = wave-uniform base + lane*16
__device__ __forceinline__ void gl2lds16(const void* g, void* l) {
    __builtin_amdgcn_global_load_lds(
        (__attribute__((address_space(1))) void*)(unsigned long long)g,
        (__attribute__((address_space(3))) void*)(u32)(unsigned long long)l,
        16, 0, 0);
}

// ---------------- LayerNorm + ReLU -> bf16 (also emits bf16 copy of x) ----------------
__global__ __launch_bounds__(256)
void ln_relu_kernel(const float* __restrict__ x, const float* __restrict__ g,
                    const float* __restrict__ b, unsigned short* __restrict__ xn,
                    unsigned short* __restrict__ xb) {
    int row = blockIdx.x;
    int tid = threadIdx.x;
    const float* xr = x + (size_t)row * CD;
    float v0 = xr[tid], v1 = xr[tid + 256], v2 = xr[tid + 512];
    float s = v0 + v1 + v2;
    __shared__ float red[8];
#pragma unroll
    for (int off = 32; off; off >>= 1) s += __shfl_down(s, off, 64);
    int lane = tid & 63, w = tid >> 6;
    if (lane == 0) red[w] = s;
    __syncthreads();
    float mean = (red[0] + red[1] + red[2] + red[3]) * (1.0f / CD);
    float d0 = v0 - mean, d1 = v1 - mean, d2 = v2 - mean;
    float s2 = d0 * d0 + d1 * d1 + d2 * d2;
#pragma unroll
    for (int off = 32; off; off >>= 1) s2 += __shfl_down(s2, off, 64);
    if (lane == 0) red[4 + w] = s2;
    __syncthreads();
    float var = (red[4] + red[5] + red[6] + red[7]) * (1.0f / CD);
    float inv = rsqrtf(var + 1e-5f);
    unsigned short* xo = xn + (size_t)row * CD;
    unsigned short* xc = xb + (size_t)row * CD;
    float o0 = fmaxf(d0 * inv * g[tid]       + b[tid],       0.0f);
    float o1 = fmaxf(d1 * inv * g[tid + 256] + b[tid + 256], 0.0f);
    float o2 = fmaxf(d2 * inv * g[tid + 512] + b[tid + 512], 0.0f);
    xo[tid] = f2bf(o0); xo[tid + 256] = f2bf(o1); xo[tid + 512] = f2bf(o2);
    xc[tid] = f2bf(v0); xc[tid + 256] = f2bf(v1); xc[tid + 512] = f2bf(v2);
}

// ---------------- Depthwise conv over T, full-T register blocking ----------------
template <int D>
__device__ __forceinline__
void dw_body(const unsigned short* __restrict__ xn, const float* __restrict__ cw,
             const float* __restrict__ cb, unsigned short* __restrict__ feat) {
    constexpr int KK = 2 * D + 1;
    int gid = blockIdx.x * 256 + threadIdx.x;     // 591*256 exact
    int bn = gid / 96;
    int cg = gid - bn * 96;
    int c0 = cg * 8;
    int b = bn / NTOK;
    size_t base = ((size_t)b * TFR * NTOK + (bn - b * NTOK)) * CD + c0;
    const size_t tstride = (size_t)NTOK * CD;

    short8 u[TFR];
#pragma unroll
    for (int t = 0; t < TFR; ++t)
        u[t] = *(const short8*)(xn + base + (size_t)t * tstride);

    float wgt[8][KK], bb[8];
#pragma unroll
    for (int q = 0; q < 8; ++q) {
        bb[q] = cb[c0 + q];
#pragma unroll
        for (int j = 0; j < KK; ++j) wgt[q][j] = cw[(c0 + q) * KK + j];
    }

#pragma unroll
    for (int t = 0; t < TFR; ++t) {
        float acc[8];
#pragma unroll
        for (int q = 0; q < 8; ++q) acc[q] = bb[q];
#pragma unroll
        for (int j = 0; j < KK; ++j) {
            int tj = t + j - D;
            if (tj < 0 || tj >= TFR) continue;   // compile-time (t,j unrolled)
#pragma unroll
            for (int q = 0; q < 8; ++q)
                acc[q] += bf2f((unsigned short)u[tj][q]) * wgt[q][j];
        }
        short8 o;
#pragma unroll
        for (int q = 0; q < 8; ++q) o[q] = (short)f2bf(acc[q]);
        *(short8*)(feat + base + (size_t)t * tstride) = o;
    }
}

// merged: blockIdx.y selects branch (d = 1,2,3)
__global__ __launch_bounds__(256)
void dwconv_all(const unsigned short* __restrict__ xn,
                const float* __restrict__ cw0, const float* __restrict__ cb0,
                const float* __restrict__ cw1, const float* __restrict__ cb1,
                const float* __restrict__ cw2, const float* __restrict__ cb2,
                unsigned short* __restrict__ f1, unsigned short* __restrict__ f2,
                unsigned short* __restrict__ f3) {
    if (blockIdx.y == 0)      dw_body<1>(xn, cw0, cb0, f1);
    else if (blockIdx.y == 1) dw_body<2>(xn, cw1, cb1, f2);
    else                      dw_body<3>(xn, cw2, cb2, f3);
}

// ---------------- weight transpose+convert: wt[n][k] = bf16(w[k][n]) ----------------
__global__ __launch_bounds__(256)
void wprep3_kernel(const float* __restrict__ w0, const float* __restrict__ w1,
                   const float* __restrict__ w2, unsigned short* __restrict__ t0,
                   unsigned short* __restrict__ t1, unsigned short* __restrict__ t2) {
    const float* w = blockIdx.y == 0 ? w0 : blockIdx.y == 1 ? w1 : w2;
    unsigned short* wt = blockIdx.y == 0 ? t0 : blockIdx.y == 1 ? t1 : t2;
    int gid = blockIdx.x * 256 + threadIdx.x;
    int n = gid / CD, k = gid - n * CD;
    wt[gid] = f2bf(w[(size_t)k * CD + n]);
}

// ---------------- fused = sum of shifted y_d (softmax weights pre-folded) ----------------
__global__ __launch_bounds__(256)
void fuse_kernel(const unsigned short* __restrict__ y1,
                 const unsigned short* __restrict__ y2,
                 const unsigned short* __restrict__ y3,
                 unsigned short* __restrict__ fused) {
    int gid = blockIdx.x * 256 + threadIdx.x;   // MROWS*96 threads, 9456 blocks exact
    int m = gid / 96;
    int kk = (gid - m * 96) * 8;
    int t = (m / NTOK) & 15;
    float vals[8] = {0.f, 0.f, 0.f, 0.f, 0.f, 0.f, 0.f, 0.f};
    const unsigned short* ys[3] = {y1, y2, y3};
#pragma unroll
    for (int d = 1; d <= 3; ++d) {
        int src; bool ok;
        if (kk < 256)      { src = m + d * NTOK; ok = (t + d) < TFR; }
        else if (kk < 512) { src = m - d * NTOK; ok = (t - d) >= 0; }
        else               { src = m;            ok = true; }
        if (ok) {
            short8 u = *(const short8*)(ys[d - 1] + (size_t)src * CD + kk);
#pragma unroll
            for (int e = 0; e < 8; ++e) vals[e] += bf2f((unsigned short)u[e]);
        }
    }
    short8 o;
#pragma unroll
    for (int e = 0; e < 8; ++e) o[e] = (short)f2bf(vals[e]);
    *(short8*)(fused + (size_t)m * CD + kk) = o;
}

// ---------------- 128x128-tile bf16 MFMA GEMM, 4-deep counted-vmcnt pipeline ----------------
// EPI 0: gate  -> bf16( wd * sigmoid(v) * xb )
// EPI 1: proj1 -> gelu -> bf16
// EPI 2: proj2 -> v + x -> fp32 out
// K-loop identical to R3 (linear LDS dest + global-source slot swizzle,
// 4 buffers, depth-3, vmcnt(8) steady state).
// Epilogue (R4): two half-passes through a padded f32 LDS bounce buffer
// (fE[64][132], aliasing the dead staging LDS) -> fully coalesced
// 16B/lane xb/xf loads and 16-32B/lane stores.
template <int EPI>
__global__ __launch_bounds__(256)
void gemm_kernel(const unsigned short* __restrict__ A,
                 const unsigned short* __restrict__ Bt,   // 768x768 bf16, N-major
                 const float* __restrict__ bias,
                 const unsigned short* __restrict__ xb,
                 const float* __restrict__ xf,
                 float* __restrict__ outf,
                 unsigned short* __restrict__ outh,
                 const float* __restrict__ fw,
                 int widx) {
    __shared__ __align__(16) char smem[65536];
    unsigned short (*As)[128 * 32] = (unsigned short (*)[128 * 32])smem;
    unsigned short (*Bs)[128 * 32] = (unsigned short (*)[128 * 32])(smem + 32768);
    float (*fE)[132] = (float (*)[132])smem;   // [64][132] = 33792 B, used post-K-loop

    int tid  = threadIdx.x;
    int m0   = blockIdx.x * 128;   // m fastest -> concurrent blocks share B n-tile
    int n0   = blockIdx.y * 128;
    int wave = tid >> 6, lane = tid & 63;
    int wm   = (wave >> 1) * 64, wn = (wave & 1) * 64;
    int quad = lane >> 4, l16 = lane & 15;
    int r4   = lane >> 2;          // 0..15: row within chunk
    // swizzled k-slot for staging: physical slot (lane&3) of row ..+r4 pulls
    // logical slot (lane&3) ^ ((r4>>1)&3)
    int ckx  = (((lane & 3) ^ ((lane >> 3) & 3)) * 8);
    // swizzled slot for fragment reads: logical slot 'quad' of row 16a+l16
    // lives at physical slot quad ^ ((l16>>1)&3)
    int rdsl = (quad ^ ((l16 >> 1) & 3)) * 8;

    const size_t arow = (size_t)(m0 + wave * 16 + r4) * CD + ckx;
    const size_t brow = (size_t)(n0 + wave * 16 + r4) * CD + ckx;
    const size_t skip = (size_t)64 * CD;   // h=1 -> chunk q+4 -> row+64

    floatx4 acc[4][4];
#pragma unroll
    for (int i = 0; i < 4; ++i)
#pragma unroll
        for (int j = 0; j < 4; ++j) acc[i][j] = (floatx4){0.f, 0.f, 0.f, 0.f};

    auto stage = [&](int t, int b) {
        const size_t ko = (size_t)t * 32;
#pragma unroll
        for (int h = 0; h < 2; ++h) {
            gl2lds16(A  + arow + h * skip + ko, &As[b][(wave + h * 4) * 512]);
            gl2lds16(Bt + brow + h * skip + ko, &Bs[b][(wave + h * 4) * 512]);
        }
    };
    auto compute = [&](int b) {
        short8 af[4], bfr[4];
#pragma unroll
        for (int i = 0; i < 4; ++i) af[i]  = *(const short8*)(&As[b][(wm + i * 16 + l16) * 32 + rdsl]);
#pragma unroll
        for (int j = 0; j < 4; ++j) bfr[j] = *(const short8*)(&Bs[b][(wn + j * 16 + l16) * 32 + rdsl]);
#pragma unroll
        for (int i = 0; i < 4; ++i)
#pragma unroll
            for (int j = 0; j < 4; ++j)
                acc[i][j] = __builtin_amdgcn_mfma_f32_16x16x32_bf16(af[i], bfr[j], acc[i][j], 0, 0, 0);
    };

    constexpr int NT = CD / 32;    // 24 K-steps
    stage(0, 0);
    stage(1, 1);
    stage(2, 2);
    for (int t = 0; t < NT - 2; ++t) {
        asm volatile("s_waitcnt vmcnt(8)" ::: "memory");   // tile t landed; t+1,t+2 in flight
        __builtin_amdgcn_s_barrier();
        __builtin_amdgcn_sched_barrier(0);
        if (t + 3 < NT) stage(t + 3, (t + 3) & 3);
        compute(t & 3);
    }
    asm volatile("s_waitcnt vmcnt(4)" ::: "memory");       // tile NT-2 landed
    __builtin_amdgcn_s_barrier();
    __builtin_amdgcn_sched_barrier(0);
    compute((NT - 2) & 3);
    asm volatile("s_waitcnt vmcnt(0)" ::: "memory");       // tile NT-1 landed
    __builtin_amdgcn_s_barrier();
    __builtin_amdgcn_sched_barrier(0);
    compute((NT - 1) & 3);

    float wd = 0.f;
    if (EPI == 0) {
        float f0 = fw[0], f1 = fw[1], f2 = fw[2];
        float mx = fmaxf(f0, fmaxf(f1, f2));
        float e0 = expf(f0 - mx), e1 = expf(f1 - mx), e2 = expf(f2 - mx);
        float inv = 1.f / (e0 + e1 + e2);
        wd = (widx == 0 ? e0 : widx == 1 ? e1 : e2) * inv;
    }

    // ---- coalesced epilogue: two half-passes through fE ----
#pragma unroll
    for (int p = 0; p < 2; ++p) {
        __syncthreads();   // K-loop LDS reads done (p=0) / prev pass reads done (p=1)
        if (wm == p * 64) {
#pragma unroll
            for (int j = 0; j < 4; ++j) {
                int col = wn + j * 16 + l16;
                float bc = bias[n0 + col];
#pragma unroll
                for (int i = 0; i < 4; ++i)
#pragma unroll
                    for (int r = 0; r < 4; ++r)
                        fE[i * 16 + quad * 4 + r][col] = acc[i][j][r] + bc;
            }
        }
        __syncthreads();
#pragma unroll
        for (int it = 0; it < 4; ++it) {
            int lr   = it * 16 + (tid >> 4);
            int cg   = tid & 15;
            size_t grow = (size_t)(m0 + p * 64 + lr);
            int gcol = n0 + cg * 8;
            size_t idx = grow * CD + gcol;
            floatx4 v0 = *(const floatx4*)&fE[lr][cg * 8];
            floatx4 v1 = *(const floatx4*)&fE[lr][cg * 8 + 4];
            if (EPI == 0) {
                short8 xv = *(const short8*)(xb + idx);
                short8 o;
#pragma unroll
                for (int e = 0; e < 8; ++e) {
                    float vv = e < 4 ? v0[e] : v1[e - 4];
                    float gte = 1.f / (1.f + expf(-vv));
                    o[e] = (short)f2bf(wd * gte * bf2f((unsigned short)xv[e]));
                }
                *(short8*)(outh + idx) = o;
            } else if (EPI == 1) {
                short8 o;
#pragma unroll
                for (int e = 0; e < 8; ++e) {
                    float vv = e < 4 ? v0[e] : v1[e - 4];
                    float gl = 0.5f * vv * (1.0f + erff(vv * 0.70710678118f));
                    o[e] = (short)f2bf(gl);
                }
                *(short8*)(outh + idx) = o;
            } else {
                floatx4 x0 = *(const floatx4*)(xf + idx);
                floatx4 x1 = *(const floatx4*)(xf + idx + 4);
#pragma unroll
                for (int e = 0; e < 4; ++e) { v0[e] += x0[e]; v1[e] += x1[e]; }
                *(floatx4*)(outf + idx)     = v0;
                *(floatx4*)(outf + idx + 4) = v1;
            }
        }
    }
}

extern "C" void kernel_launch(void* const* d_in, const int* in_sizes, int n_in,
                              void* d_out, int out_size, void* d_ws, size_t ws_size,
                              hipStream_t stream) {
    const float* x      = (const float*)d_in[0];
    const float* ln_g   = (const float*)d_in[1];
    const float* ln_b   = (const float*)d_in[2];
    const float* gate_w = (const float*)d_in[3];
    const float* gate_b = (const float*)d_in[4];
    const float* pw1    = (const float*)d_in[5];
    const float* pb1    = (const float*)d_in[6];
    const float* pw2    = (const float*)d_in[7];
    const float* pb2    = (const float*)d_in[8];
    const float* fw     = (const float*)d_in[9];
    const float* cw[3]  = {(const float*)d_in[11], (const float*)d_in[13], (const float*)d_in[15]};
    const float* cb[3]  = {(const float*)d_in[12], (const float*)d_in[14], (const float*)d_in[16]};

    char* ws = (char*)d_ws;
    const size_t SB = (size_t)MROWS * CD * 2;                   // 38,731,776
    unsigned short* gwt  = (unsigned short*)(ws + 0);
    unsigned short* p1t  = (unsigned short*)(ws + 1179648);
    unsigned short* p2t  = (unsigned short*)(ws + 2359296);
    unsigned short* xn   = (unsigned short*)(ws + 3538944);            // -> y1, h1
    unsigned short* xb   = (unsigned short*)(ws + 3538944 + SB);
    unsigned short* f1   = (unsigned short*)(ws + 3538944 + 2 * SB);   // -> y2
    unsigned short* f2   = (unsigned short*)(ws + 3538944 + 3 * SB);   // -> y3
    unsigned short* f3   = (unsigned short*)(ws + 3538944 + 4 * SB);   // -> fused
    unsigned short* y1    = xn;   // xn dead after dwconv_all
    unsigned short* y2    = f1;   // f1 dead after gate1
    unsigned short* y3    = f2;   // f2 dead after gate2
    unsigned short* fused = f3;   // f3 dead after gate3
    unsigned short* h1    = xn;   // y1 dead after fuse
    // total: 3,538,944 + 5*SB = 197,197,824 bytes

    dim3 wg(2304, 3);
    wprep3_kernel<<<wg, 256, 0, stream>>>(gate_w, pw1, pw2, gwt, p1t, p2t);
    ln_relu_kernel<<<MROWS, 256, 0, stream>>>(x, ln_g, ln_b, xn, xb);

    dim3 dg(591, 3);
    dwconv_all<<<dg, 256, 0, stream>>>(xn, cw[0], cb[0], cw[1], cb[1], cw[2], cb[2],
                                       f1, f2, f3);

    dim3 gg(197, 6);   // m-tiles fastest: concurrent blocks share one B n-tile
    gemm_kernel<0><<<gg, 256, 0, stream>>>(f1, gwt, gate_b, xb, nullptr,
                                           nullptr, y1, fw, 0);
    gemm_kernel<0><<<gg, 256, 0, stream>>>(f2, gwt, gate_b, xb, nullptr,
                                           nullptr, y2, fw, 1);
    gemm_kernel<0><<<gg, 256, 0, stream>>>(f3, gwt, gate_b, xb, nullptr,
                                           nullptr, y3, fw, 2);

    fuse_kernel<<<9456, 256, 0, stream>>>(y1, y2, y3, fused);

    gemm_kernel<1><<<gg, 256, 0, stream>>>(fused, p1t, pb1, nullptr, nullptr,
                                           nullptr, h1, nullptr, 0);
    gemm_kernel<2><<<gg, 256, 0, stream>>>(h1, p2t, pb2, nullptr, x,
                                           (float*)d_out, nullptr, nullptr, 0);
}

// Round 5
// 549.519 us; speedup vs baseline: 1.3182x; 1.0098x over previous
//
#include <hip/hip_runtime.h>
#include <math.h>

// MultiScaleTransformerGSM on MI355X (gfx950).
// LN+ReLU(+bf16 x copy) -> merged dwconv(3 branches) -> merged gate GEMM
// (3 branches, one dispatch) -> fusion materialization -> proj1 GEMM ->
// proj2 GEMM + residual.
// R1: fused tensor materialized once; LDS double-buffer.
// R2: counted-vmcnt pipeline (3 buffers, depth-2, vmcnt(4)).
// R3: global-source bank-conflict swizzle (conflicts -> 0); depth-3 vmcnt(8).
// R4: coalesced epilogue via LDS f32 bounce; merged dwconv.
// R5: (a) T3/T5 phase-split K-step: two barrier-delimited sub-phases per
//         K-step, each {ds_read subtile || gl2lds stage-half -> lgkm0 ->
//         setprio(1) MFMA-cluster setprio(0)}; vmcnt counting identical to R4.
//     (b) 3 gate GEMMs merged into ONE dispatch (A = contiguous f1|f2|f3,
//         grid (591,6), branch = blockIdx.x/197).

#define MROWS 25216   // B*T*N = 8*16*197
#define CD    768
#define NTOK  197
#define TFR   16

typedef __attribute__((ext_vector_type(8))) short short8;
typedef __attribute__((ext_vector_type(4))) float floatx4;
typedef unsigned int u32;

__device__ __forceinline__ unsigned short f2bf(float f) {
    union { float f; unsigned u; } v; v.f = f;
    unsigned r = v.u + 0x7FFFu + ((v.u >> 16) & 1u);
    return (unsigned short)(r >> 16);
}
__device__ __forceinline__ float bf2f(unsigned short h) {
    union { unsigned u; float f; } v; v.u = ((unsigned)h) << 16;
    return v.f;
}

// async global->LDS, 16B per lane; LDS dest = wave-uniform base + lane*16
__device__ __forceinline__ void gl2lds16(const void* g, void* l) {
    __builtin_amdgcn_global_load_lds(
        (__attribute__((address_space(1))) void*)(unsigned long long)g,
        (__attribute__((address_space(3))) void*)(u32)(unsigned long long)l,
        16, 0, 0);
}

// ---------------- LayerNorm + ReLU -> bf16 (also emits bf16 copy of x) ----------------
__global__ __launch_bounds__(256)
void ln_relu_kernel(const float* __restrict__ x, const float* __restrict__ g,
                    const float* __restrict__ b, unsigned short* __restrict__ xn,
                    unsigned short* __restrict__ xb) {
    int row = blockIdx.x;
    int tid = threadIdx.x;
    const float* xr = x + (size_t)row * CD;
    float v0 = xr[tid], v1 = xr[tid + 256], v2 = xr[tid + 512];
    float s = v0 + v1 + v2;
    __shared__ float red[8];
#pragma unroll
    for (int off = 32; off; off >>= 1) s += __shfl_down(s, off, 64);
    int lane = tid & 63, w = tid >> 6;
    if (lane == 0) red[w] = s;
    __syncthreads();
    float mean = (red[0] + red[1] + red[2] + red[3]) * (1.0f / CD);
    float d0 = v0 - mean, d1 = v1 - mean, d2 = v2 - mean;
    float s2 = d0 * d0 + d1 * d1 + d2 * d2;
#pragma unroll
    for (int off = 32; off; off >>= 1) s2 += __shfl_down(s2, off, 64);
    if (lane == 0) red[4 + w] = s2;
    __syncthreads();
    float var = (red[4] + red[5] + red[6] + red[7]) * (1.0f / CD);
    float inv = rsqrtf(var + 1e-5f);
    unsigned short* xo = xn + (size_t)row * CD;
    unsigned short* xc = xb + (size_t)row * CD;
    float o0 = fmaxf(d0 * inv * g[tid]       + b[tid],       0.0f);
    float o1 = fmaxf(d1 * inv * g[tid + 256] + b[tid + 256], 0.0f);
    float o2 = fmaxf(d2 * inv * g[tid + 512] + b[tid + 512], 0.0f);
    xo[tid] = f2bf(o0); xo[tid + 256] = f2bf(o1); xo[tid + 512] = f2bf(o2);
    xc[tid] = f2bf(v0); xc[tid + 256] = f2bf(v1); xc[tid + 512] = f2bf(v2);
}

// ---------------- Depthwise conv over T, full-T register blocking ----------------
template <int D>
__device__ __forceinline__
void dw_body(const unsigned short* __restrict__ xn, const float* __restrict__ cw,
             const float* __restrict__ cb, unsigned short* __restrict__ feat) {
    constexpr int KK = 2 * D + 1;
    int gid = blockIdx.x * 256 + threadIdx.x;     // 591*256 exact
    int bn = gid / 96;
    int cg = gid - bn * 96;
    int c0 = cg * 8;
    int b = bn / NTOK;
    size_t base = ((size_t)b * TFR * NTOK + (bn - b * NTOK)) * CD + c0;
    const size_t tstride = (size_t)NTOK * CD;

    short8 u[TFR];
#pragma unroll
    for (int t = 0; t < TFR; ++t)
        u[t] = *(const short8*)(xn + base + (size_t)t * tstride);

    float wgt[8][KK], bb[8];
#pragma unroll
    for (int q = 0; q < 8; ++q) {
        bb[q] = cb[c0 + q];
#pragma unroll
        for (int j = 0; j < KK; ++j) wgt[q][j] = cw[(c0 + q) * KK + j];
    }

#pragma unroll
    for (int t = 0; t < TFR; ++t) {
        float acc[8];
#pragma unroll
        for (int q = 0; q < 8; ++q) acc[q] = bb[q];
#pragma unroll
        for (int j = 0; j < KK; ++j) {
            int tj = t + j - D;
            if (tj < 0 || tj >= TFR) continue;   // compile-time (t,j unrolled)
#pragma unroll
            for (int q = 0; q < 8; ++q)
                acc[q] += bf2f((unsigned short)u[tj][q]) * wgt[q][j];
        }
        short8 o;
#pragma unroll
        for (int q = 0; q < 8; ++q) o[q] = (short)f2bf(acc[q]);
        *(short8*)(feat + base + (size_t)t * tstride) = o;
    }
}

// merged: blockIdx.y selects branch (d = 1,2,3)
__global__ __launch_bounds__(256)
void dwconv_all(const unsigned short* __restrict__ xn,
                const float* __restrict__ cw0, const float* __restrict__ cb0,
                const float* __restrict__ cw1, const float* __restrict__ cb1,
                const float* __restrict__ cw2, const float* __restrict__ cb2,
                unsigned short* __restrict__ f1, unsigned short* __restrict__ f2,
                unsigned short* __restrict__ f3) {
    if (blockIdx.y == 0)      dw_body<1>(xn, cw0, cb0, f1);
    else if (blockIdx.y == 1) dw_body<2>(xn, cw1, cb1, f2);
    else                      dw_body<3>(xn, cw2, cb2, f3);
}

// ---------------- weight transpose+convert: wt[n][k] = bf16(w[k][n]) ----------------
__global__ __launch_bounds__(256)
void wprep3_kernel(const float* __restrict__ w0, const float* __restrict__ w1,
                   const float* __restrict__ w2, unsigned short* __restrict__ t0,
                   unsigned short* __restrict__ t1, unsigned short* __restrict__ t2) {
    const float* w = blockIdx.y == 0 ? w0 : blockIdx.y == 1 ? w1 : w2;
    unsigned short* wt = blockIdx.y == 0 ? t0 : blockIdx.y == 1 ? t1 : t2;
    int gid = blockIdx.x * 256 + threadIdx.x;
    int n = gid / CD, k = gid - n * CD;
    wt[gid] = f2bf(w[(size_t)k * CD + n]);
}

// ---------------- fused = sum of shifted y_d (softmax weights pre-folded) ----------------
__global__ __launch_bounds__(256)
void fuse_kernel(const unsigned short* __restrict__ y1,
                 const unsigned short* __restrict__ y2,
                 const unsigned short* __restrict__ y3,
                 unsigned short* __restrict__ fused) {
    int gid = blockIdx.x * 256 + threadIdx.x;   // MROWS*96 threads, 9456 blocks exact
    int m = gid / 96;
    int kk = (gid - m * 96) * 8;
    int t = (m / NTOK) & 15;
    float vals[8] = {0.f, 0.f, 0.f, 0.f, 0.f, 0.f, 0.f, 0.f};
    const unsigned short* ys[3] = {y1, y2, y3};
#pragma unroll
    for (int d = 1; d <= 3; ++d) {
        int src; bool ok;
        if (kk < 256)      { src = m + d * NTOK; ok = (t + d) < TFR; }
        else if (kk < 512) { src = m - d * NTOK; ok = (t - d) >= 0; }
        else               { src = m;            ok = true; }
        if (ok) {
            short8 u = *(const short8*)(ys[d - 1] + (size_t)src * CD + kk);
#pragma unroll
            for (int e = 0; e < 8; ++e) vals[e] += bf2f((unsigned short)u[e]);
        }
    }
    short8 o;
#pragma unroll
    for (int e = 0; e < 8; ++e) o[e] = (short)f2bf(vals[e]);
    *(short8*)(fused + (size_t)m * CD + kk) = o;
}

// ---------------- 128x128-tile bf16 MFMA GEMM, phase-split counted-vmcnt pipeline ----------------
// EPI 0: gate  -> bf16( wd * sigmoid(v) * xb ); 3 branches in one dispatch
//        (A has NB*MROWS rows; branch = m0/MROWS; output ptr + wd per branch)
// EPI 1: proj1 -> gelu -> bf16
// EPI 2: proj2 -> v + x -> fp32 out
// K-loop: R4's layout/swizzle/vmcnt counting, restructured as two sub-phases
// per K-step (T3):   vmcnt(8); bar;
//   P1: ds_read A0..3 + B0,1 || stage-half h=0 of t+3 -> lgkm0 -> prio1 8 MFMA prio0
//   bar;
//   P2: ds_read B2,3        || stage-half h=1 of t+3 -> lgkm0 -> prio1 8 MFMA prio0
// Loads per K-step and their program order are identical to R4 -> same
// retirement math (vmcnt(8) steady, 4/0 peel) and same buffer-reuse proof.
template <int EPI>
__global__ __launch_bounds__(256)
void gemm_kernel(const unsigned short* __restrict__ A,
                 const unsigned short* __restrict__ Bt,   // 768x768 bf16, N-major
                 const float* __restrict__ bias,
                 const unsigned short* __restrict__ xb,
                 const float* __restrict__ xf,
                 float* __restrict__ outf,
                 unsigned short* __restrict__ outh0,
                 unsigned short* __restrict__ outh1,
                 unsigned short* __restrict__ outh2,
                 const float* __restrict__ fw) {
    __shared__ __align__(16) char smem[65536];
    unsigned short (*As)[128 * 32] = (unsigned short (*)[128 * 32])smem;
    unsigned short (*Bs)[128 * 32] = (unsigned short (*)[128 * 32])(smem + 32768);
    float (*fE)[132] = (float (*)[132])smem;   // [64][132] = 33792 B, used post-K-loop

    int tid  = threadIdx.x;
    int m0   = blockIdx.x * 128;   // m fastest -> concurrent blocks share B n-tile
    int n0   = blockIdx.y * 128;
    int widx = blockIdx.x / (MROWS / 128);     // gate: 0..2 ; proj: 0
    int wave = tid >> 6, lane = tid & 63;
    int wm   = (wave >> 1) * 64, wn = (wave & 1) * 64;
    int quad = lane >> 4, l16 = lane & 15;
    int r4   = lane >> 2;          // 0..15: row within chunk
    // swizzled k-slot for staging: physical slot (lane&3) of row ..+r4 pulls
    // logical slot (lane&3) ^ ((r4>>1)&3)
    int ckx  = (((lane & 3) ^ ((lane >> 3) & 3)) * 8);
    // swizzled slot for fragment reads: logical slot 'quad' of row 16a+l16
    // lives at physical slot quad ^ ((l16>>1)&3)
    int rdsl = (quad ^ ((l16 >> 1) & 3)) * 8;

    const size_t arow = (size_t)(m0 + wave * 16 + r4) * CD + ckx;
    const size_t brow = (size_t)(n0 + wave * 16 + r4) * CD + ckx;
    const size_t skip = (size_t)64 * CD;   // h=1 -> chunk q+4 -> row+64

    floatx4 acc[4][4];
#pragma unroll
    for (int i = 0; i < 4; ++i)
#pragma unroll
        for (int j = 0; j < 4; ++j) acc[i][j] = (floatx4){0.f, 0.f, 0.f, 0.f};

    auto stage_h = [&](int t, int b, int h) {
        const size_t ko = (size_t)t * 32;
        gl2lds16(A  + arow + h * skip + ko, &As[b][(wave + h * 4) * 512]);
        gl2lds16(Bt + brow + h * skip + ko, &Bs[b][(wave + h * 4) * 512]);
    };
    auto stage = [&](int t, int b) { stage_h(t, b, 0); stage_h(t, b, 1); };

    constexpr int NT = CD / 32;    // 24 K-steps

    auto kstep = [&](int t, bool doStage) {
        int b = t & 3;
        short8 af[4], bfr[4];
        // ---- phase 1: A frags + B j0,j1 ; stage half h=0 of t+3 ----
#pragma unroll
        for (int i = 0; i < 4; ++i)
            af[i] = *(const short8*)(&As[b][(wm + i * 16 + l16) * 32 + rdsl]);
        bfr[0] = *(const short8*)(&Bs[b][(wn + 0 * 16 + l16) * 32 + rdsl]);
        bfr[1] = *(const short8*)(&Bs[b][(wn + 1 * 16 + l16) * 32 + rdsl]);
        if (doStage) stage_h(t + 3, (t + 3) & 3, 0);
        asm volatile("s_waitcnt lgkmcnt(0)" ::: "memory");
        __builtin_amdgcn_sched_barrier(0);
        __builtin_amdgcn_s_setprio(1);
#pragma unroll
        for (int i = 0; i < 4; ++i) {
            acc[i][0] = __builtin_amdgcn_mfma_f32_16x16x32_bf16(af[i], bfr[0], acc[i][0], 0, 0, 0);
            acc[i][1] = __builtin_amdgcn_mfma_f32_16x16x32_bf16(af[i], bfr[1], acc[i][1], 0, 0, 0);
        }
        __builtin_amdgcn_s_setprio(0);
        __builtin_amdgcn_s_barrier();
        __builtin_amdgcn_sched_barrier(0);
        // ---- phase 2: B j2,j3 ; stage half h=1 of t+3 ----
        bfr[2] = *(const short8*)(&Bs[b][(wn + 2 * 16 + l16) * 32 + rdsl]);
        bfr[3] = *(const short8*)(&Bs[b][(wn + 3 * 16 + l16) * 32 + rdsl]);
        if (doStage) stage_h(t + 3, (t + 3) & 3, 1);
        asm volatile("s_waitcnt lgkmcnt(0)" ::: "memory");
        __builtin_amdgcn_sched_barrier(0);
        __builtin_amdgcn_s_setprio(1);
#pragma unroll
        for (int i = 0; i < 4; ++i) {
            acc[i][2] = __builtin_amdgcn_mfma_f32_16x16x32_bf16(af[i], bfr[2], acc[i][2], 0, 0, 0);
            acc[i][3] = __builtin_amdgcn_mfma_f32_16x16x32_bf16(af[i], bfr[3], acc[i][3], 0, 0, 0);
        }
        __builtin_amdgcn_s_setprio(0);
    };

    stage(0, 0);
    stage(1, 1);
    stage(2, 2);
    for (int t = 0; t < NT - 2; ++t) {
        asm volatile("s_waitcnt vmcnt(8)" ::: "memory");   // tile t landed; t+1,t+2 in flight
        __builtin_amdgcn_s_barrier();
        __builtin_amdgcn_sched_barrier(0);
        kstep(t, t + 3 < NT);
    }
    asm volatile("s_waitcnt vmcnt(4)" ::: "memory");       // tile NT-2 landed
    __builtin_amdgcn_s_barrier();
    __builtin_amdgcn_sched_barrier(0);
    kstep(NT - 2, false);
    asm volatile("s_waitcnt vmcnt(0)" ::: "memory");       // tile NT-1 landed
    __builtin_amdgcn_s_barrier();
    __builtin_amdgcn_sched_barrier(0);
    kstep(NT - 1, false);

    float wd = 0.f;
    unsigned short* outh = outh0;
    if (EPI == 0) {
        float f0 = fw[0], f1 = fw[1], f2 = fw[2];
        float mx = fmaxf(f0, fmaxf(f1, f2));
        float e0 = expf(f0 - mx), e1 = expf(f1 - mx), e2 = expf(f2 - mx);
        float inv = 1.f / (e0 + e1 + e2);
        wd = (widx == 0 ? e0 : widx == 1 ? e1 : e2) * inv;
        outh = widx == 0 ? outh0 : widx == 1 ? outh1 : outh2;
    }
    const size_t lshift = (size_t)widx * MROWS * CD;   // global->per-branch row base

    // ---- coalesced epilogue: two half-passes through fE ----
#pragma unroll
    for (int p = 0; p < 2; ++p) {
        __syncthreads();   // K-loop LDS reads done (p=0) / prev pass reads done (p=1)
        if (wm == p * 64) {
#pragma unroll
            for (int j = 0; j < 4; ++j) {
                int col = wn + j * 16 + l16;
                float bc = bias[n0 + col];
#pragma unroll
                for (int i = 0; i < 4; ++i)
#pragma unroll
                    for (int r = 0; r < 4; ++r)
                        fE[i * 16 + quad * 4 + r][col] = acc[i][j][r] + bc;
            }
        }
        __syncthreads();
#pragma unroll
        for (int it = 0; it < 4; ++it) {
            int lr   = it * 16 + (tid >> 4);
            int cg   = tid & 15;
            size_t grow = (size_t)(m0 + p * 64 + lr);
            int gcol = n0 + cg * 8;
            size_t idx = grow * CD + gcol - lshift;   // per-branch row index
            floatx4 v0 = *(const floatx4*)&fE[lr][cg * 8];
            floatx4 v1 = *(const floatx4*)&fE[lr][cg * 8 + 4];
            if (EPI == 0) {
                short8 xv = *(const short8*)(xb + idx);
                short8 o;
#pragma unroll
                for (int e = 0; e < 8; ++e) {
                    float vv = e < 4 ? v0[e] : v1[e - 4];
                    float gte = 1.f / (1.f + expf(-vv));
                    o[e] = (short)f2bf(wd * gte * bf2f((unsigned short)xv[e]));
                }
                *(short8*)(outh + idx) = o;
            } else if (EPI == 1) {
                short8 o;
#pragma unroll
                for (int e = 0; e < 8; ++e) {
                    float vv = e < 4 ? v0[e] : v1[e - 4];
                    float gl = 0.5f * vv * (1.0f + erff(vv * 0.70710678118f));
                    o[e] = (short)f2bf(gl);
                }
                *(short8*)(outh + idx) = o;
            } else {
                floatx4 x0 = *(const floatx4*)(xf + idx);
                floatx4 x1 = *(const floatx4*)(xf + idx + 4);
#pragma unroll
                for (int e = 0; e < 4; ++e) { v0[e] += x0[e]; v1[e] += x1[e]; }
                *(floatx4*)(outf + idx)     = v0;
                *(floatx4*)(outf + idx + 4) = v1;
            }
        }
    }
}

extern "C" void kernel_launch(void* const* d_in, const int* in_sizes, int n_in,
                              void* d_out, int out_size, void* d_ws, size_t ws_size,
                              hipStream_t stream) {
    const float* x      = (const float*)d_in[0];
    const float* ln_g   = (const float*)d_in[1];
    const float* ln_b   = (const float*)d_in[2];
    const float* gate_w = (const float*)d_in[3];
    const float* gate_b = (const float*)d_in[4];
    const float* pw1    = (const float*)d_in[5];
    const float* pb1    = (const float*)d_in[6];
    const float* pw2    = (const float*)d_in[7];
    const float* pb2    = (const float*)d_in[8];
    const float* fw     = (const float*)d_in[9];
    const float* cw[3]  = {(const float*)d_in[11], (const float*)d_in[13], (const float*)d_in[15]};
    const float* cb[3]  = {(const float*)d_in[12], (const float*)d_in[14], (const float*)d_in[16]};

    char* ws = (char*)d_ws;
    const size_t SB = (size_t)MROWS * CD * 2;                   // 38,731,776
    unsigned short* gwt  = (unsigned short*)(ws + 0);
    unsigned short* p1t  = (unsigned short*)(ws + 1179648);
    unsigned short* p2t  = (unsigned short*)(ws + 2359296);
    unsigned short* xn   = (unsigned short*)(ws + 3538944);            // -> y1, h1
    unsigned short* xb   = (unsigned short*)(ws + 3538944 + SB);
    unsigned short* f1   = (unsigned short*)(ws + 3538944 + 2 * SB);   // -> y2
    unsigned short* f2   = (unsigned short*)(ws + 3538944 + 3 * SB);   // -> y3
    unsigned short* f3   = (unsigned short*)(ws + 3538944 + 4 * SB);   // -> fused
    unsigned short* y1    = xn;   // xn dead after dwconv_all
    unsigned short* y2    = f1;   // f1 dead after merged gate (A row-blocks
    unsigned short* y3    = f2;   //   are read before their y is written:
    unsigned short* fused = f3;   //   y_d rows only alias f_(d+1) rows)
    unsigned short* h1    = xn;   // y1 dead after fuse
    // total: 3,538,944 + 5*SB = 197,197,824 bytes

    dim3 wg(2304, 3);
    wprep3_kernel<<<wg, 256, 0, stream>>>(gate_w, pw1, pw2, gwt, p1t, p2t);
    ln_relu_kernel<<<MROWS, 256, 0, stream>>>(x, ln_g, ln_b, xn, xb);

    dim3 dg(591, 3);
    dwconv_all<<<dg, 256, 0, stream>>>(xn, cw[0], cb[0], cw[1], cb[1], cw[2], cb[2],
                                       f1, f2, f3);

    // merged gate GEMM: A = contiguous [f1; f2; f3] (75648 rows), one dispatch.
    // NOTE aliasing: y1=xn (not an A source), y2=f1 (written by branch 1 whose
    // A is f2), y3=f2 (written by branch 2 whose A is f3) -- a y-row write
    // aliases a DIFFERENT branch's A rows. Branch b's A-tile (row-block) is
    // consumed strictly before branch b-1's same-numbered... to be safe,
    // m-tiles ordered branch-major ascending and each block reads only its own
    // A rows (f_{widx+1}) while writing y_{widx}: y2 writes hit f1 (branch 0's
    // A, already fully consumed only if branch 0 blocks ran first -- NOT
    // guaranteed). So: keep y-buffers NON-aliased with A sources instead:
    dim3 gg3(591, 6);
    // y1->xn (safe), y2/y3 must not alias f1..f3: reuse xb? xb is read by the
    // gate epilogue itself. Allocate y2,y3 past f3:
    unsigned short* y2s = (unsigned short*)(ws + 3538944 + 5 * SB);
    unsigned short* y3s = (unsigned short*)(ws + 3538944 + 6 * SB);
    // total now: 3,538,944 + 7*SB = 274,661,376 bytes
    gemm_kernel<0><<<gg3, 256, 0, stream>>>(f1, gwt, gate_b, xb, nullptr,
                                            nullptr, y1, y2s, y3s, fw);

    fuse_kernel<<<9456, 256, 0, stream>>>(y1, y2s, y3s, fused);

    dim3 gg(197, 6);   // m-tiles fastest: concurrent blocks share one B n-tile
    gemm_kernel<1><<<gg, 256, 0, stream>>>(fused, p1t, pb1, nullptr, nullptr,
                                           nullptr, h1, nullptr, nullptr, nullptr);
    gemm_kernel<2><<<gg, 256, 0, stream>>>(h1, p2t, pb2, nullptr, x,
                                           (float*)d_out, nullptr, nullptr, nullptr, nullptr);
}

// Round 6
// 529.189 us; speedup vs baseline: 1.3688x; 1.0384x over previous
//
#include <hip/hip_runtime.h>
#include <math.h>

// MultiScaleTransformerGSM on MI355X (gfx950).
// LN+ReLU(+bf16 x copy) -> merged dwconv(3) -> merged gate GEMM -> fusion
// materialization -> proj1 GEMM -> proj2 GEMM + residual.
// R1: fused materialized once.  R2: counted-vmcnt.  R3: swizzle (conflicts->0).
// R4: coalesced LDS-bounce epilogue (WRITE = ideal).  R5: phase-split+setprio.
// R6: 8-phase-template port: BM=128 x BN=256, BK=64, 512 thr / 8 waves
//     (2Mx4N, 64x64/wave), 3 x 48KB LDS buffers (144KB dynamic), 4 sub-phases
//     per K-step {ds_read || gl2lds -> lgkm0 -> prio1 8xMFMA prio0 -> bar},
//     ONE vmcnt(6) per K-step (depth-2 tiles, 6 loads/tile/wave).
//     N=768 -> 3 n-tiles, M=75648 -> 591 m-tiles: no masking anywhere.

#define MROWS 25216   // B*T*N = 8*16*197
#define CD    768
#define NTOK  197
#define TFR   16

typedef __attribute__((ext_vector_type(8))) short short8;
typedef __attribute__((ext_vector_type(4))) float floatx4;
typedef unsigned int u32;

__device__ __forceinline__ unsigned short f2bf(float f) {
    union { float f; unsigned u; } v; v.f = f;
    unsigned r = v.u + 0x7FFFu + ((v.u >> 16) & 1u);
    return (unsigned short)(r >> 16);
}
__device__ __forceinline__ float bf2f(unsigned short h) {
    union { unsigned u; float f; } v; v.u = ((unsigned)h) << 16;
    return v.f;
}

// async global->LDS, 16B per lane; LDS dest = wave-uniform base + lane*16
__device__ __forceinline__ void gl2lds16(const void* g, void* l) {
    __builtin_amdgcn_global_load_lds(
        (__attribute__((address_space(1))) void*)(unsigned long long)g,
        (__attribute__((address_space(3))) void*)(u32)(unsigned long long)l,
        16, 0, 0);
}

// ---------------- LayerNorm + ReLU -> bf16 (also emits bf16 copy of x) ----------------
__global__ __launch_bounds__(256)
void ln_relu_kernel(const float* __restrict__ x, const float* __restrict__ g,
                    const float* __restrict__ b, unsigned short* __restrict__ xn,
                    unsigned short* __restrict__ xb) {
    int row = blockIdx.x;
    int tid = threadIdx.x;
    const float* xr = x + (size_t)row * CD;
    float v0 = xr[tid], v1 = xr[tid + 256], v2 = xr[tid + 512];
    float s = v0 + v1 + v2;
    __shared__ float red[8];
#pragma unroll
    for (int off = 32; off; off >>= 1) s += __shfl_down(s, off, 64);
    int lane = tid & 63, w = tid >> 6;
    if (lane == 0) red[w] = s;
    __syncthreads();
    float mean = (red[0] + red[1] + red[2] + red[3]) * (1.0f / CD);
    float d0 = v0 - mean, d1 = v1 - mean, d2 = v2 - mean;
    float s2 = d0 * d0 + d1 * d1 + d2 * d2;
#pragma unroll
    for (int off = 32; off; off >>= 1) s2 += __shfl_down(s2, off, 64);
    if (lane == 0) red[4 + w] = s2;
    __syncthreads();
    float var = (red[4] + red[5] + red[6] + red[7]) * (1.0f / CD);
    float inv = rsqrtf(var + 1e-5f);
    unsigned short* xo = xn + (size_t)row * CD;
    unsigned short* xc = xb + (size_t)row * CD;
    float o0 = fmaxf(d0 * inv * g[tid]       + b[tid],       0.0f);
    float o1 = fmaxf(d1 * inv * g[tid + 256] + b[tid + 256], 0.0f);
    float o2 = fmaxf(d2 * inv * g[tid + 512] + b[tid + 512], 0.0f);
    xo[tid] = f2bf(o0); xo[tid + 256] = f2bf(o1); xo[tid + 512] = f2bf(o2);
    xc[tid] = f2bf(v0); xc[tid + 256] = f2bf(v1); xc[tid + 512] = f2bf(v2);
}

// ---------------- Depthwise conv over T, full-T register blocking ----------------
template <int D>
__device__ __forceinline__
void dw_body(const unsigned short* __restrict__ xn, const float* __restrict__ cw,
             const float* __restrict__ cb, unsigned short* __restrict__ feat) {
    constexpr int KK = 2 * D + 1;
    int gid = blockIdx.x * 256 + threadIdx.x;     // 591*256 exact
    int bn = gid / 96;
    int cg = gid - bn * 96;
    int c0 = cg * 8;
    int b = bn / NTOK;
    size_t base = ((size_t)b * TFR * NTOK + (bn - b * NTOK)) * CD + c0;
    const size_t tstride = (size_t)NTOK * CD;

    short8 u[TFR];
#pragma unroll
    for (int t = 0; t < TFR; ++t)
        u[t] = *(const short8*)(xn + base + (size_t)t * tstride);

    float wgt[8][KK], bb[8];
#pragma unroll
    for (int q = 0; q < 8; ++q) {
        bb[q] = cb[c0 + q];
#pragma unroll
        for (int j = 0; j < KK; ++j) wgt[q][j] = cw[(c0 + q) * KK + j];
    }

#pragma unroll
    for (int t = 0; t < TFR; ++t) {
        float acc[8];
#pragma unroll
        for (int q = 0; q < 8; ++q) acc[q] = bb[q];
#pragma unroll
        for (int j = 0; j < KK; ++j) {
            int tj = t + j - D;
            if (tj < 0 || tj >= TFR) continue;   // compile-time (t,j unrolled)
#pragma unroll
            for (int q = 0; q < 8; ++q)
                acc[q] += bf2f((unsigned short)u[tj][q]) * wgt[q][j];
        }
        short8 o;
#pragma unroll
        for (int q = 0; q < 8; ++q) o[q] = (short)f2bf(acc[q]);
        *(short8*)(feat + base + (size_t)t * tstride) = o;
    }
}

__global__ __launch_bounds__(256)
void dwconv_all(const unsigned short* __restrict__ xn,
                const float* __restrict__ cw0, const float* __restrict__ cb0,
                const float* __restrict__ cw1, const float* __restrict__ cb1,
                const float* __restrict__ cw2, const float* __restrict__ cb2,
                unsigned short* __restrict__ f1, unsigned short* __restrict__ f2,
                unsigned short* __restrict__ f3) {
    if (blockIdx.y == 0)      dw_body<1>(xn, cw0, cb0, f1);
    else if (blockIdx.y == 1) dw_body<2>(xn, cw1, cb1, f2);
    else                      dw_body<3>(xn, cw2, cb2, f3);
}

// ---------------- weight transpose+convert: wt[n][k] = bf16(w[k][n]) ----------------
__global__ __launch_bounds__(256)
void wprep3_kernel(const float* __restrict__ w0, const float* __restrict__ w1,
                   const float* __restrict__ w2, unsigned short* __restrict__ t0,
                   unsigned short* __restrict__ t1, unsigned short* __restrict__ t2) {
    const float* w = blockIdx.y == 0 ? w0 : blockIdx.y == 1 ? w1 : w2;
    unsigned short* wt = blockIdx.y == 0 ? t0 : blockIdx.y == 1 ? t1 : t2;
    int gid = blockIdx.x * 256 + threadIdx.x;
    int n = gid / CD, k = gid - n * CD;
    wt[gid] = f2bf(w[(size_t)k * CD + n]);
}

// ---------------- fused = sum of shifted y_d (softmax weights pre-folded) ----------------
__global__ __launch_bounds__(256)
void fuse_kernel(const unsigned short* __restrict__ y1,
                 const unsigned short* __restrict__ y2,
                 const unsigned short* __restrict__ y3,
                 unsigned short* __restrict__ fused) {
    int gid = blockIdx.x * 256 + threadIdx.x;   // MROWS*96 threads, 9456 blocks exact
    int m = gid / 96;
    int kk = (gid - m * 96) * 8;
    int t = (m / NTOK) & 15;
    float vals[8] = {0.f, 0.f, 0.f, 0.f, 0.f, 0.f, 0.f, 0.f};
    const unsigned short* ys[3] = {y1, y2, y3};
#pragma unroll
    for (int d = 1; d <= 3; ++d) {
        int src; bool ok;
        if (kk < 256)      { src = m + d * NTOK; ok = (t + d) < TFR; }
        else if (kk < 512) { src = m - d * NTOK; ok = (t - d) >= 0; }
        else               { src = m;            ok = true; }
        if (ok) {
            short8 u = *(const short8*)(ys[d - 1] + (size_t)src * CD + kk);
#pragma unroll
            for (int e = 0; e < 8; ++e) vals[e] += bf2f((unsigned short)u[e]);
        }
    }
    short8 o;
#pragma unroll
    for (int e = 0; e < 8; ++e) o[e] = (short)f2bf(vals[e]);
    *(short8*)(fused + (size_t)m * CD + kk) = o;
}

// ---------------- 128x256-tile, BK=64, 8-wave, 4-sub-phase MFMA GEMM ----------------
// EPI 0: gate (3 branches merged, branch = blockIdx.x/197) -> bf16(wd*sig(v)*xb)
// EPI 1: proj1 -> gelu -> bf16       EPI 2: proj2 -> v + x -> fp32
// LDS (dynamic 147456B): As[3] 16KB @ b*16384, Bs[3] 32KB @ 49152+b*32768.
// Row-major [rows][64] bf16 (128B rows, 8 slots of 16B). Chunk = 8 rows = 1KB;
// wave w stages chunks {w+8h}; lane i lands row q*8+(i>>3), phys slot i&7,
// sourcing global k-slot (i&7)^(i>>3)  -> phys slot p holds logical p^(row&7).
// ds_read: logical slot kk*4+quad at phys (kk*4+quad)^(l16&7): within each
// 16-lane b128 phase-group all 8 slot-columns hit distinct 4-bank groups,
// 2 lanes each = conflict-free.
// Pipeline: 3 buffers, depth-2 tiles (12 loads/wave in flight), vmcnt(6) once
// per K-step; stage(t+2) spread over phases P0-P2 (overwrites the buffer all
// waves finished at step t-1, published by the top-of-step barrier).
// Epilogue: single-pass f32 bounce fE[128][268] over the dead 144KB.
template <int EPI>
__global__ __launch_bounds__(512)
void gemm_kernel(const unsigned short* __restrict__ A,
                 const unsigned short* __restrict__ Bt,   // 768x768 bf16, N-major
                 const float* __restrict__ bias,
                 const unsigned short* __restrict__ xb,
                 const float* __restrict__ xf,
                 float* __restrict__ outf,
                 unsigned short* __restrict__ outh0,
                 unsigned short* __restrict__ outh1,
                 unsigned short* __restrict__ outh2,
                 const float* __restrict__ fw) {
    extern __shared__ __align__(16) char smem[];
    int tid  = threadIdx.x;
    int m0   = blockIdx.x * 128;   // m fastest -> concurrent blocks share B n-tile
    int n0   = blockIdx.y * 256;
    int wave = tid >> 6, lane = tid & 63;
    int wr   = wave >> 2, wc = wave & 3;     // 2M x 4N wave grid, 64x64 each
    int quad = lane >> 4, l16 = lane & 15;
    int rr   = lane >> 3;                    // row within 8-row staging chunk
    int ckx  = ((lane & 7) ^ rr) * 8;        // swizzled global k-slot (shorts)

    floatx4 acc[4][4];
#pragma unroll
    for (int i = 0; i < 4; ++i)
#pragma unroll
        for (int j = 0; j < 4; ++j) acc[i][j] = (floatx4){0.f, 0.f, 0.f, 0.f};

    auto Asb = [&](int bb) { return (unsigned short*)(smem + bb * 16384); };
    auto Bsb = [&](int bb) { return (unsigned short*)(smem + 49152 + bb * 32768); };

    auto sA = [&](int t, int bb, int h) {
        int q = wave + h * 8;                // 0..15
        gl2lds16(A + (size_t)(m0 + q * 8 + rr) * CD + t * 64 + ckx, Asb(bb) + q * 512);
    };
    auto sB = [&](int t, int bb, int h) {
        int q = wave + h * 8;                // 0..31
        gl2lds16(Bt + (size_t)(n0 + q * 8 + rr) * CD + t * 64 + ckx, Bsb(bb) + q * 512);
    };
    auto ldA = [&](int bb, int i, int kk) -> short8 {
        int r = wr * 64 + i * 16 + l16;
        int slot = (kk * 4 + quad) ^ (l16 & 7);
        return *(const short8*)((const char*)Asb(bb) + r * 128 + slot * 16);
    };
    auto ldB = [&](int bb, int j, int kk) -> short8 {
        int r = wc * 64 + j * 16 + l16;
        int slot = (kk * 4 + quad) ^ (l16 & 7);
        return *(const short8*)((const char*)Bsb(bb) + r * 128 + slot * 16);
    };

#define LGKM0 do { asm volatile("s_waitcnt lgkmcnt(0)" ::: "memory"); \
                   __builtin_amdgcn_sched_barrier(0); } while (0)
#define PBAR  do { __builtin_amdgcn_s_barrier(); \
                   __builtin_amdgcn_sched_barrier(0); } while (0)

    auto kstep = [&](int t, bool doStage) {
        int bb = t % 3, bn = (t + 2) % 3;
        short8 a0[4], a1[4], u, v;
        // ---- P0: A kk0 (4) + B j0,j1 kk0 ; stage A halves of t+2 ----
#pragma unroll
        for (int i = 0; i < 4; ++i) a0[i] = ldA(bb, i, 0);
        u = ldB(bb, 0, 0); v = ldB(bb, 1, 0);
        if (doStage) { sA(t + 2, bn, 0); sA(t + 2, bn, 1); }
        LGKM0;
        __builtin_amdgcn_s_setprio(1);
#pragma unroll
        for (int i = 0; i < 4; ++i) {
            acc[i][0] = __builtin_amdgcn_mfma_f32_16x16x32_bf16(a0[i], u, acc[i][0], 0, 0, 0);
            acc[i][1] = __builtin_amdgcn_mfma_f32_16x16x32_bf16(a0[i], v, acc[i][1], 0, 0, 0);
        }
        __builtin_amdgcn_s_setprio(0);
        PBAR;
        // ---- P1: B j2,j3 kk0 ; stage B halves 0,1 ----
        u = ldB(bb, 2, 0); v = ldB(bb, 3, 0);
        if (doStage) { sB(t + 2, bn, 0); sB(t + 2, bn, 1); }
        LGKM0;
        __builtin_amdgcn_s_setprio(1);
#pragma unroll
        for (int i = 0; i < 4; ++i) {
            acc[i][2] = __builtin_amdgcn_mfma_f32_16x16x32_bf16(a0[i], u, acc[i][2], 0, 0, 0);
            acc[i][3] = __builtin_amdgcn_mfma_f32_16x16x32_bf16(a0[i], v, acc[i][3], 0, 0, 0);
        }
        __builtin_amdgcn_s_setprio(0);
        PBAR;
        // ---- P2: A kk1 (4) + B j0,j1 kk1 ; stage B halves 2,3 ----
#pragma unroll
        for (int i = 0; i < 4; ++i) a1[i] = ldA(bb, i, 1);
        u = ldB(bb, 0, 1); v = ldB(bb, 1, 1);
        if (doStage) { sB(t + 2, bn, 2); sB(t + 2, bn, 3); }
        LGKM0;
        __builtin_amdgcn_s_setprio(1);
#pragma unroll
        for (int i = 0; i < 4; ++i) {
            acc[i][0] = __builtin_amdgcn_mfma_f32_16x16x32_bf16(a1[i], u, acc[i][0], 0, 0, 0);
            acc[i][1] = __builtin_amdgcn_mfma_f32_16x16x32_bf16(a1[i], v, acc[i][1], 0, 0, 0);
        }
        __builtin_amdgcn_s_setprio(0);
        PBAR;
        // ---- P3: B j2,j3 kk1 ----
        u = ldB(bb, 2, 1); v = ldB(bb, 3, 1);
        LGKM0;
        __builtin_amdgcn_s_setprio(1);
#pragma unroll
        for (int i = 0; i < 4; ++i) {
            acc[i][2] = __builtin_amdgcn_mfma_f32_16x16x32_bf16(a1[i], u, acc[i][2], 0, 0, 0);
            acc[i][3] = __builtin_amdgcn_mfma_f32_16x16x32_bf16(a1[i], v, acc[i][3], 0, 0, 0);
        }
        __builtin_amdgcn_s_setprio(0);
    };

    constexpr int NT = CD / 64;    // 12 K-steps
    // prologue: tiles 0,1 (6 loads each per wave)
    sA(0, 0, 0); sA(0, 0, 1); sB(0, 0, 0); sB(0, 0, 1); sB(0, 0, 2); sB(0, 0, 3);
    sA(1, 1, 0); sA(1, 1, 1); sB(1, 1, 0); sB(1, 1, 1); sB(1, 1, 2); sB(1, 1, 3);
    for (int t = 0; t < NT - 1; ++t) {
        asm volatile("s_waitcnt vmcnt(6)" ::: "memory");   // tile t landed; t+1 in flight
        PBAR;
        kstep(t, t + 2 < NT);
    }
    asm volatile("s_waitcnt vmcnt(0)" ::: "memory");       // last tile landed
    PBAR;
    kstep(NT - 1, false);

    float wd = 0.f;
    int widx = (EPI == 0) ? (blockIdx.x / 197) : 0;
    unsigned short* outh = outh0;
    if (EPI == 0) {
        float f0 = fw[0], f1 = fw[1], f2 = fw[2];
        float mx = fmaxf(f0, fmaxf(f1, f2));
        float e0 = expf(f0 - mx), e1 = expf(f1 - mx), e2 = expf(f2 - mx);
        float inv = 1.f / (e0 + e1 + e2);
        wd = (widx == 0 ? e0 : widx == 1 ? e1 : e2) * inv;
        outh = widx == 0 ? outh0 : widx == 1 ? outh1 : outh2;
    }

    // ---- single-pass coalesced epilogue through fE[128][268] ----
    float (*fE)[268] = (float (*)[268])smem;
    __syncthreads();   // all K-loop LDS reads retired before overwrite
#pragma unroll
    for (int j = 0; j < 4; ++j) {
        int col = wc * 64 + j * 16 + l16;
        float bc = bias[n0 + col];
#pragma unroll
        for (int i = 0; i < 4; ++i)
#pragma unroll
            for (int r = 0; r < 4; ++r)
                fE[wr * 64 + i * 16 + quad * 4 + r][col] = acc[i][j][r] + bc;
    }
    __syncthreads();
#pragma unroll
    for (int it = 0; it < 8; ++it) {
        int lr = it * 16 + (tid >> 5);
        int cg = tid & 31;
        size_t lrow = (size_t)(m0 + lr) - (size_t)widx * MROWS;  // per-branch row
        int gcol = n0 + cg * 8;
        size_t idx = lrow * CD + gcol;
        floatx4 v0 = *(const floatx4*)&fE[lr][cg * 8];
        floatx4 v1 = *(const floatx4*)&fE[lr][cg * 8 + 4];
        if (EPI == 0) {
            short8 xv = *(const short8*)(xb + idx);
            short8 o;
#pragma unroll
            for (int e = 0; e < 8; ++e) {
                float vv = e < 4 ? v0[e] : v1[e - 4];
                float gte = 1.f / (1.f + expf(-vv));
                o[e] = (short)f2bf(wd * gte * bf2f((unsigned short)xv[e]));
            }
            *(short8*)(outh + idx) = o;
        } else if (EPI == 1) {
            short8 o;
#pragma unroll
            for (int e = 0; e < 8; ++e) {
                float vv = e < 4 ? v0[e] : v1[e - 4];
                float gl = 0.5f * vv * (1.0f + erff(vv * 0.70710678118f));
                o[e] = (short)f2bf(gl);
            }
            *(short8*)(outh + idx) = o;
        } else {
            floatx4 x0 = *(const floatx4*)(xf + idx);
            floatx4 x1 = *(const floatx4*)(xf + idx + 4);
#pragma unroll
            for (int e = 0; e < 4; ++e) { v0[e] += x0[e]; v1[e] += x1[e]; }
            *(floatx4*)(outf + idx)     = v0;
            *(floatx4*)(outf + idx + 4) = v1;
        }
    }
#undef LGKM0
#undef PBAR
}

extern "C" void kernel_launch(void* const* d_in, const int* in_sizes, int n_in,
                              void* d_out, int out_size, void* d_ws, size_t ws_size,
                              hipStream_t stream) {
    const float* x      = (const float*)d_in[0];
    const float* ln_g   = (const float*)d_in[1];
    const float* ln_b   = (const float*)d_in[2];
    const float* gate_w = (const float*)d_in[3];
    const float* gate_b = (const float*)d_in[4];
    const float* pw1    = (const float*)d_in[5];
    const float* pb1    = (const float*)d_in[6];
    const float* pw2    = (const float*)d_in[7];
    const float* pb2    = (const float*)d_in[8];
    const float* fw     = (const float*)d_in[9];
    const float* cw[3]  = {(const float*)d_in[11], (const float*)d_in[13], (const float*)d_in[15]};
    const float* cb[3]  = {(const float*)d_in[12], (const float*)d_in[14], (const float*)d_in[16]};

    char* ws = (char*)d_ws;
    const size_t SB = (size_t)MROWS * CD * 2;                   // 38,731,776
    unsigned short* gwt  = (unsigned short*)(ws + 0);
    unsigned short* p1t  = (unsigned short*)(ws + 1179648);
    unsigned short* p2t  = (unsigned short*)(ws + 2359296);
    unsigned short* xn   = (unsigned short*)(ws + 3538944);
    unsigned short* xb   = (unsigned short*)(ws + 3538944 + SB);
    unsigned short* f1   = (unsigned short*)(ws + 3538944 + 2 * SB);   // A0 (merged gate)
    unsigned short* f2   = (unsigned short*)(ws + 3538944 + 3 * SB);   // A1
    unsigned short* f3   = (unsigned short*)(ws + 3538944 + 4 * SB);   // A2
    unsigned short* y2s  = (unsigned short*)(ws + 3538944 + 5 * SB);
    unsigned short* y3s  = (unsigned short*)(ws + 3538944 + 6 * SB);
    unsigned short* y1    = xn;   // xn dead after dwconv_all
    unsigned short* fused = f3;   // f3 dead after gate GEMM (branch 2 reads f3,
                                  //   writes y3s; fused written by fuse_kernel after)
    unsigned short* h1    = xn;   // y1 dead after fuse
    // total: 3,538,944 + 7*SB = 274,661,376 bytes

    const int LDSB = 147456;
    hipFuncSetAttribute(reinterpret_cast<const void*>(gemm_kernel<0>),
                        hipFuncAttributeMaxDynamicSharedMemorySize, LDSB);
    hipFuncSetAttribute(reinterpret_cast<const void*>(gemm_kernel<1>),
                        hipFuncAttributeMaxDynamicSharedMemorySize, LDSB);
    hipFuncSetAttribute(reinterpret_cast<const void*>(gemm_kernel<2>),
                        hipFuncAttributeMaxDynamicSharedMemorySize, LDSB);

    dim3 wg(2304, 3);
    wprep3_kernel<<<wg, 256, 0, stream>>>(gate_w, pw1, pw2, gwt, p1t, p2t);
    ln_relu_kernel<<<MROWS, 256, 0, stream>>>(x, ln_g, ln_b, xn, xb);

    dim3 dg(591, 3);
    dwconv_all<<<dg, 256, 0, stream>>>(xn, cw[0], cb[0], cw[1], cb[1], cw[2], cb[2],
                                       f1, f2, f3);

    // merged gate GEMM: A = contiguous [f1; f2; f3] = 75648 rows = 591 m-tiles.
    dim3 gg3(591, 3);
    gemm_kernel<0><<<gg3, 512, LDSB, stream>>>(f1, gwt, gate_b, xb, nullptr,
                                               nullptr, y1, y2s, y3s, fw);

    fuse_kernel<<<9456, 256, 0, stream>>>(y1, y2s, y3s, fused);

    dim3 gg(197, 3);   // m-tiles fastest: concurrent blocks share one B n-tile
    gemm_kernel<1><<<gg, 512, LDSB, stream>>>(fused, p1t, pb1, nullptr, nullptr,
                                              nullptr, h1, nullptr, nullptr, nullptr);
    gemm_kernel<2><<<gg, 512, LDSB, stream>>>(h1, p2t, pb2, nullptr, x,
                                              (float*)d_out, nullptr, nullptr, nullptr, nullptr);
}

// Round 7
// 485.775 us; speedup vs baseline: 1.4911x; 1.0894x over previous
//
#include <hip/hip_runtime.h>
#include <math.h>

// MultiScaleTransformerGSM on MI355X (gfx950).
// fused LN+ReLU+dwconv(3) -> merged gate GEMM -> fusion materialization ->
// proj1 GEMM -> proj2 GEMM + residual.
// R1: fused tensor materialized once.  R2: counted-vmcnt.  R3: swizzle->0 conflicts.
// R4: coalesced LDS-bounce epilogue.   R5: phase-split+setprio.
// R6: BM128xBN256 template, BK=64, 144KB LDS (1 block/CU -- occupancy-capped).
// R7: (a) BK=32, 3x24KB LDS buffers (72KB) -> 2 blocks/CU (independent barrier
//         domains double TLP); __launch_bounds__(512,4); R3-proven swizzle.
//     (b) LN+ReLU fused INTO dwconv (xn tensor eliminated: -155MB HBM).
//     (c) __expf sigmoid epilogue (libm expf was ~half the epilogue VALU).

#define MROWS 25216   // B*T*N = 8*16*197
#define CD    768
#define NTOK  197
#define TFR   16

typedef __attribute__((ext_vector_type(8))) short short8;
typedef __attribute__((ext_vector_type(4))) short short4v;
typedef __attribute__((ext_vector_type(4))) float floatx4;
typedef unsigned int u32;

__device__ __forceinline__ unsigned short f2bf(float f) {
    union { float f; unsigned u; } v; v.f = f;
    unsigned r = v.u + 0x7FFFu + ((v.u >> 16) & 1u);
    return (unsigned short)(r >> 16);
}
__device__ __forceinline__ float bf2f(unsigned short h) {
    union { unsigned u; float f; } v; v.u = ((unsigned)h) << 16;
    return v.f;
}

// async global->LDS, 16B per lane; LDS dest = wave-uniform base + lane*16
__device__ __forceinline__ void gl2lds16(const void* g, void* l) {
    __builtin_amdgcn_global_load_lds(
        (__attribute__((address_space(1))) void*)(unsigned long long)g,
        (__attribute__((address_space(3))) void*)(u32)(unsigned long long)l,
        16, 0, 0);
}

// ---------------- fused LayerNorm+ReLU+dwconv (3 branches) + bf16 x copy ----------------
// Block = 192 threads = one (b,n) unit; thread owns 4 channels across all T=16.
// LN in f32 registers (wave shfl + LDS cross-wave reduce), conv over T in regs.
// Eliminates the xn tensor entirely.
template <int D>
__device__ __forceinline__
void dw_store(const float (&xn)[TFR][4], const float* __restrict__ cw,
              const float* __restrict__ cb, unsigned short* __restrict__ f,
              size_t base, size_t tstr, int c0) {
    constexpr int KK = 2 * D + 1;
    float wj[4][KK], cbv[4];
#pragma unroll
    for (int q = 0; q < 4; ++q) {
        cbv[q] = cb[c0 + q];
#pragma unroll
        for (int j = 0; j < KK; ++j) wj[q][j] = cw[(c0 + q) * KK + j];
    }
#pragma unroll
    for (int t = 0; t < TFR; ++t) {
        float acc[4] = {cbv[0], cbv[1], cbv[2], cbv[3]};
#pragma unroll
        for (int j = 0; j < KK; ++j) {
            int tj = t + j - D;
            if (tj < 0 || tj >= TFR) continue;   // compile-time
#pragma unroll
            for (int q = 0; q < 4; ++q) acc[q] += xn[tj][q] * wj[q][j];
        }
        short4v o;
#pragma unroll
        for (int q = 0; q < 4; ++q) o[q] = (short)f2bf(acc[q]);
        *(short4v*)(f + base + t * tstr) = o;
    }
}

__global__ __launch_bounds__(192)
void ln_dw_kernel(const float* __restrict__ x, const float* __restrict__ g,
                  const float* __restrict__ bia,
                  const float* __restrict__ cw0, const float* __restrict__ cb0,
                  const float* __restrict__ cw1, const float* __restrict__ cb1,
                  const float* __restrict__ cw2, const float* __restrict__ cb2,
                  unsigned short* __restrict__ xb,
                  unsigned short* __restrict__ f1,
                  unsigned short* __restrict__ f2,
                  unsigned short* __restrict__ f3) {
    int blk = blockIdx.x, tid = threadIdx.x;   // 1576 blocks (8*197)
    int b = blk / NTOK, n = blk - b * NTOK;
    int c0 = tid * 4;
    size_t base = ((size_t)b * TFR * NTOK + n) * CD + c0;
    const size_t tstr = (size_t)NTOK * CD;
    int lane = tid & 63, w = tid >> 6;

    float xn[TFR][4];
    float ps[TFR];
#pragma unroll
    for (int t = 0; t < TFR; ++t) {
        float4 xv = *(const float4*)(x + base + t * tstr);
        xn[t][0] = xv.x; xn[t][1] = xv.y; xn[t][2] = xv.z; xn[t][3] = xv.w;
        ps[t] = xv.x + xv.y + xv.z + xv.w;
        short4v o; o[0] = (short)f2bf(xv.x); o[1] = (short)f2bf(xv.y);
        o[2] = (short)f2bf(xv.z); o[3] = (short)f2bf(xv.w);
        *(short4v*)(xb + base + t * tstr) = o;
    }
    __shared__ float red[TFR][4];
#pragma unroll
    for (int t = 0; t < TFR; ++t) {
        float v = ps[t];
#pragma unroll
        for (int off = 32; off; off >>= 1) v += __shfl_down(v, off, 64);
        if (lane == 0) red[t][w] = v;
    }
    __syncthreads();
    float mean[TFR];
#pragma unroll
    for (int t = 0; t < TFR; ++t) mean[t] = (red[t][0] + red[t][1] + red[t][2]) * (1.0f / CD);
    __syncthreads();
#pragma unroll
    for (int t = 0; t < TFR; ++t) {
        float d0 = xn[t][0] - mean[t], d1 = xn[t][1] - mean[t];
        float d2 = xn[t][2] - mean[t], d3 = xn[t][3] - mean[t];
        ps[t] = d0 * d0 + d1 * d1 + d2 * d2 + d3 * d3;
    }
#pragma unroll
    for (int t = 0; t < TFR; ++t) {
        float v = ps[t];
#pragma unroll
        for (int off = 32; off; off >>= 1) v += __shfl_down(v, off, 64);
        if (lane == 0) red[t][w] = v;
    }
    __syncthreads();
    float gv[4], bv[4];
#pragma unroll
    for (int q = 0; q < 4; ++q) { gv[q] = g[c0 + q]; bv[q] = bia[c0 + q]; }
#pragma unroll
    for (int t = 0; t < TFR; ++t) {
        float var = (red[t][0] + red[t][1] + red[t][2]) * (1.0f / CD);
        float inv = rsqrtf(var + 1e-5f);
#pragma unroll
        for (int q = 0; q < 4; ++q)
            xn[t][q] = fmaxf((xn[t][q] - mean[t]) * inv * gv[q] + bv[q], 0.0f);
    }
    dw_store<1>(xn, cw0, cb0, f1, base, tstr, c0);
    dw_store<2>(xn, cw1, cb1, f2, base, tstr, c0);
    dw_store<3>(xn, cw2, cb2, f3, base, tstr, c0);
}

// ---------------- weight transpose+convert: wt[n][k] = bf16(w[k][n]) ----------------
__global__ __launch_bounds__(256)
void wprep3_kernel(const float* __restrict__ w0, const float* __restrict__ w1,
                   const float* __restrict__ w2, unsigned short* __restrict__ t0,
                   unsigned short* __restrict__ t1, unsigned short* __restrict__ t2) {
    const float* w = blockIdx.y == 0 ? w0 : blockIdx.y == 1 ? w1 : w2;
    unsigned short* wt = blockIdx.y == 0 ? t0 : blockIdx.y == 1 ? t1 : t2;
    int gid = blockIdx.x * 256 + threadIdx.x;
    int n = gid / CD, k = gid - n * CD;
    wt[gid] = f2bf(w[(size_t)k * CD + n]);
}

// ---------------- fused = sum of shifted y_d (softmax weights pre-folded) ----------------
__global__ __launch_bounds__(256)
void fuse_kernel(const unsigned short* __restrict__ y1,
                 const unsigned short* __restrict__ y2,
                 const unsigned short* __restrict__ y3,
                 unsigned short* __restrict__ fused) {
    int gid = blockIdx.x * 256 + threadIdx.x;   // 9456 blocks exact
    int m = gid / 96;
    int kk = (gid - m * 96) * 8;
    int t = (m / NTOK) & 15;
    float vals[8] = {0.f, 0.f, 0.f, 0.f, 0.f, 0.f, 0.f, 0.f};
    const unsigned short* ys[3] = {y1, y2, y3};
#pragma unroll
    for (int d = 1; d <= 3; ++d) {
        int src; bool ok;
        if (kk < 256)      { src = m + d * NTOK; ok = (t + d) < TFR; }
        else if (kk < 512) { src = m - d * NTOK; ok = (t - d) >= 0; }
        else               { src = m;            ok = true; }
        if (ok) {
            short8 u = *(const short8*)(ys[d - 1] + (size_t)src * CD + kk);
#pragma unroll
            for (int e = 0; e < 8; ++e) vals[e] += bf2f((unsigned short)u[e]);
        }
    }
    short8 o;
#pragma unroll
    for (int e = 0; e < 8; ++e) o[e] = (short)f2bf(vals[e]);
    *(short8*)(fused + (size_t)m * CD + kk) = o;
}

// ---------------- 128x256-tile, BK=32, 8-wave, 2-block/CU MFMA GEMM ----------------
// EPI 0: gate (3 branches merged) -> bf16(wd*sig(v)*xb)
// EPI 1: proj1 -> gelu -> bf16       EPI 2: proj2 -> v + x -> fp32
// LDS dynamic 73728B: As[3] 8KB @ bb*8192, Bs[3] 16KB @ 24576+bb*16384.
// Rows are 64B (32 bf16); staging chunk = 16 rows = 1KB: lane i -> row i>>2,
// phys slot i&3, global k-slot (i&3)^((i>>3)&3) -> phys p holds logical
// p^((row>>1)&3).  ds_read slot = quad^((l16>>1)&3): 16-lane phase covers 8
// distinct (row-parity, slot) -> 2 lanes/bank = free (R3-measured 0 conflicts).
// Pipeline: 3 buffers, depth-2 (6 loads/wave in flight), vmcnt(3) steady /
// vmcnt(0) peel; stage(t+2) inside step t overwrites the buffer all waves
// finished at t-1 (published by the top-of-step barrier).
// 2 sub-phases/K-step, each {ds_read || stage -> lgkm0 -> prio1 8xMFMA prio0}.
// 72KB x 2 = 144KB <= 160KB and 128 VGPR/thread cap -> 2 blocks/CU.
template <int EPI>
__global__ __launch_bounds__(512, 4)
void gemm_kernel(const unsigned short* __restrict__ A,
                 const unsigned short* __restrict__ Bt,   // 768x768 bf16, N-major
                 const float* __restrict__ bias,
                 const unsigned short* __restrict__ xb,
                 const float* __restrict__ xf,
                 float* __restrict__ outf,
                 unsigned short* __restrict__ outh0,
                 unsigned short* __restrict__ outh1,
                 unsigned short* __restrict__ outh2,
                 const float* __restrict__ fw) {
    extern __shared__ __align__(16) char smem[];
    int tid  = threadIdx.x;
    int m0   = blockIdx.x * 128;   // m fastest
    int n0   = blockIdx.y * 256;
    int wave = tid >> 6, lane = tid & 63;
    int wr   = wave >> 2, wc = wave & 3;     // 2M x 4N waves, 64x64 each
    int quad = lane >> 4, l16 = lane & 15;
    int r4   = lane >> 2;
    int ckx  = (((lane & 3) ^ ((lane >> 3) & 3)) * 8);   // global k-slot (shorts)
    int rdsl = (quad ^ ((l16 >> 1) & 3)) * 16;           // read slot (bytes)

    floatx4 acc[4][4];
#pragma unroll
    for (int i = 0; i < 4; ++i)
#pragma unroll
        for (int j = 0; j < 4; ++j) acc[i][j] = (floatx4){0.f, 0.f, 0.f, 0.f};

    auto Asb = [&](int bb) { return smem + bb * 8192; };
    auto Bsb = [&](int bb) { return smem + 24576 + bb * 16384; };

    const size_t aoff = (size_t)(m0 + wave * 16 + r4) * CD + ckx;
    const size_t boff = (size_t)(n0 + wave * 16 + r4) * CD + ckx;
    auto sA = [&](int t, int bb) {
        gl2lds16(A + aoff + t * 32, Asb(bb) + wave * 1024);
    };
    auto sB = [&](int t, int bb, int h) {
        gl2lds16(Bt + boff + (size_t)h * 128 * CD + t * 32, Bsb(bb) + (wave + h * 8) * 1024);
    };
    auto ldA = [&](int bb, int i) -> short8 {
        return *(const short8*)(Asb(bb) + (wr * 64 + i * 16 + l16) * 64 + rdsl);
    };
    auto ldB = [&](int bb, int j) -> short8 {
        return *(const short8*)(Bsb(bb) + (wc * 64 + j * 16 + l16) * 64 + rdsl);
    };

#define LGKM0 do { asm volatile("s_waitcnt lgkmcnt(0)" ::: "memory"); \
                   __builtin_amdgcn_sched_barrier(0); } while (0)
#define PBAR  do { __builtin_amdgcn_s_barrier(); \
                   __builtin_amdgcn_sched_barrier(0); } while (0)

    auto kstep = [&](int t, bool doStage) {
        int bb = t % 3, bnx = (t + 2) % 3;
        short8 a[4], u, v;
        // ---- P0: A(4) + B j0,j1 ; stage A + B-half0 of t+2 ----
#pragma unroll
        for (int i = 0; i < 4; ++i) a[i] = ldA(bb, i);
        u = ldB(bb, 0); v = ldB(bb, 1);
        if (doStage) { sA(t + 2, bnx); sB(t + 2, bnx, 0); }
        LGKM0;
        __builtin_amdgcn_s_setprio(1);
#pragma unroll
        for (int i = 0; i < 4; ++i) {
            acc[i][0] = __builtin_amdgcn_mfma_f32_16x16x32_bf16(a[i], u, acc[i][0], 0, 0, 0);
            acc[i][1] = __builtin_amdgcn_mfma_f32_16x16x32_bf16(a[i], v, acc[i][1], 0, 0, 0);
        }
        __builtin_amdgcn_s_setprio(0);
        PBAR;
        // ---- P1: B j2,j3 ; stage B-half1 of t+2 ----
        u = ldB(bb, 2); v = ldB(bb, 3);
        if (doStage) sB(t + 2, bnx, 1);
        LGKM0;
        __builtin_amdgcn_s_setprio(1);
#pragma unroll
        for (int i = 0; i < 4; ++i) {
            acc[i][2] = __builtin_amdgcn_mfma_f32_16x16x32_bf16(a[i], u, acc[i][2], 0, 0, 0);
            acc[i][3] = __builtin_amdgcn_mfma_f32_16x16x32_bf16(a[i], v, acc[i][3], 0, 0, 0);
        }
        __builtin_amdgcn_s_setprio(0);
    };

    constexpr int NT = CD / 32;    // 24 K-steps
    sA(0, 0); sB(0, 0, 0); sB(0, 0, 1);
    sA(1, 1); sB(1, 1, 0); sB(1, 1, 1);
    for (int t = 0; t < NT - 1; ++t) {
        asm volatile("s_waitcnt vmcnt(3)" ::: "memory");   // tile t landed; t+1 in flight
        PBAR;
        kstep(t, t + 2 < NT);
    }
    asm volatile("s_waitcnt vmcnt(0)" ::: "memory");       // last tile landed
    PBAR;
    kstep(NT - 1, false);

    float wd = 0.f;
    int widx = (EPI == 0) ? (blockIdx.x / 197) : 0;
    unsigned short* outh = outh0;
    if (EPI == 0) {
        float f0 = fw[0], f1 = fw[1], f2 = fw[2];
        float mx = fmaxf(f0, fmaxf(f1, f2));
        float e0 = __expf(f0 - mx), e1 = __expf(f1 - mx), e2 = __expf(f2 - mx);
        float inv = 1.f / (e0 + e1 + e2);
        wd = (widx == 0 ? e0 : widx == 1 ? e1 : e2) * inv;
        outh = widx == 0 ? outh0 : widx == 1 ? outh1 : outh2;
    }

    // ---- coalesced epilogue: two half-passes through fE[64][264] (67.6KB) ----
    float (*fE)[264] = (float (*)[264])smem;
#pragma unroll
    for (int p = 0; p < 2; ++p) {
        __syncthreads();   // K-loop reads done (p=0) / prev pass reads done (p=1)
        if (wr == p) {
#pragma unroll
            for (int j = 0; j < 4; ++j) {
                int col = wc * 64 + j * 16 + l16;
                float bc = bias[n0 + col];
#pragma unroll
                for (int i = 0; i < 4; ++i)
#pragma unroll
                    for (int r = 0; r < 4; ++r)
                        fE[i * 16 + quad * 4 + r][col] = acc[i][j][r] + bc;
            }
        }
        __syncthreads();
#pragma unroll
        for (int it = 0; it < 4; ++it) {
            int lr = it * 16 + (tid >> 5);
            int cg = tid & 31;
            size_t lrow = (size_t)(m0 + p * 64 + lr) - (size_t)widx * MROWS;
            size_t idx = lrow * CD + n0 + cg * 8;
            floatx4 v0 = *(const floatx4*)&fE[lr][cg * 8];
            floatx4 v1 = *(const floatx4*)&fE[lr][cg * 8 + 4];
            if (EPI == 0) {
                short8 xv = *(const short8*)(xb + idx);
                short8 o;
#pragma unroll
                for (int e = 0; e < 8; ++e) {
                    float vv = e < 4 ? v0[e] : v1[e - 4];
                    float gte = 1.f / (1.f + __expf(-vv));
                    o[e] = (short)f2bf(wd * gte * bf2f((unsigned short)xv[e]));
                }
                *(short8*)(outh + idx) = o;
            } else if (EPI == 1) {
                short8 o;
#pragma unroll
                for (int e = 0; e < 8; ++e) {
                    float vv = e < 4 ? v0[e] : v1[e - 4];
                    float gl = 0.5f * vv * (1.0f + erff(vv * 0.70710678118f));
                    o[e] = (short)f2bf(gl);
                }
                *(short8*)(outh + idx) = o;
            } else {
                floatx4 x0 = *(const floatx4*)(xf + idx);
                floatx4 x1 = *(const floatx4*)(xf + idx + 4);
#pragma unroll
                for (int e = 0; e < 4; ++e) { v0[e] += x0[e]; v1[e] += x1[e]; }
                *(floatx4*)(outf + idx)     = v0;
                *(floatx4*)(outf + idx + 4) = v1;
            }
        }
    }
#undef LGKM0
#undef PBAR
}

extern "C" void kernel_launch(void* const* d_in, const int* in_sizes, int n_in,
                              void* d_out, int out_size, void* d_ws, size_t ws_size,
                              hipStream_t stream) {
    const float* x      = (const float*)d_in[0];
    const float* ln_g   = (const float*)d_in[1];
    const float* ln_b   = (const float*)d_in[2];
    const float* gate_w = (const float*)d_in[3];
    const float* gate_b = (const float*)d_in[4];
    const float* pw1    = (const float*)d_in[5];
    const float* pb1    = (const float*)d_in[6];
    const float* pw2    = (const float*)d_in[7];
    const float* pb2    = (const float*)d_in[8];
    const float* fw     = (const float*)d_in[9];
    const float* cw[3]  = {(const float*)d_in[11], (const float*)d_in[13], (const float*)d_in[15]};
    const float* cb[3]  = {(const float*)d_in[12], (const float*)d_in[14], (const float*)d_in[16]};

    char* ws = (char*)d_ws;
    const size_t SB = (size_t)MROWS * CD * 2;                   // 38,731,776
    unsigned short* gwt  = (unsigned short*)(ws + 0);
    unsigned short* p1t  = (unsigned short*)(ws + 1179648);
    unsigned short* p2t  = (unsigned short*)(ws + 2359296);
    unsigned short* y1   = (unsigned short*)(ws + 3538944);            // scratch slot
    unsigned short* xb   = (unsigned short*)(ws + 3538944 + SB);
    unsigned short* f1   = (unsigned short*)(ws + 3538944 + 2 * SB);   // A0 (merged gate)
    unsigned short* f2   = (unsigned short*)(ws + 3538944 + 3 * SB);   // A1
    unsigned short* f3   = (unsigned short*)(ws + 3538944 + 4 * SB);   // A2
    unsigned short* y2s  = (unsigned short*)(ws + 3538944 + 5 * SB);
    unsigned short* y3s  = (unsigned short*)(ws + 3538944 + 6 * SB);
    unsigned short* fused = f3;   // f3 dead after gate GEMM (stream-ordered)
    unsigned short* h1    = y1;   // y1 dead after fuse_kernel
    // total: 3,538,944 + 7*SB = 274,661,376 bytes

    const int LDSB = 73728;
    hipFuncSetAttribute(reinterpret_cast<const void*>(gemm_kernel<0>),
                        hipFuncAttributeMaxDynamicSharedMemorySize, LDSB);
    hipFuncSetAttribute(reinterpret_cast<const void*>(gemm_kernel<1>),
                        hipFuncAttributeMaxDynamicSharedMemorySize, LDSB);
    hipFuncSetAttribute(reinterpret_cast<const void*>(gemm_kernel<2>),
                        hipFuncAttributeMaxDynamicSharedMemorySize, LDSB);

    dim3 wg(2304, 3);
    wprep3_kernel<<<wg, 256, 0, stream>>>(gate_w, pw1, pw2, gwt, p1t, p2t);

    ln_dw_kernel<<<8 * NTOK, 192, 0, stream>>>(x, ln_g, ln_b,
                                               cw[0], cb[0], cw[1], cb[1], cw[2], cb[2],
                                               xb, f1, f2, f3);

    // merged gate GEMM: A = contiguous [f1; f2; f3] = 75648 rows = 591 m-tiles.
    dim3 gg3(591, 3);
    gemm_kernel<0><<<gg3, 512, LDSB, stream>>>(f1, gwt, gate_b, xb, nullptr,
                                               nullptr, y1, y2s, y3s, fw);

    fuse_kernel<<<9456, 256, 0, stream>>>(y1, y2s, y3s, fused);

    dim3 gg(197, 3);
    gemm_kernel<1><<<gg, 512, LDSB, stream>>>(fused, p1t, pb1, nullptr, nullptr,
                                              nullptr, h1, nullptr, nullptr, nullptr);
    gemm_kernel<2><<<gg, 512, LDSB, stream>>>(h1, p2t, pb2, nullptr, x,
                                              (float*)d_out, nullptr, nullptr, nullptr, nullptr);
}